// Round 1
// baseline (11331.500 us; speedup 1.0000x reference)
//
#include <hip/hip_runtime.h>

#define NU 50000
#define NV 50000
#define ES 800000
#define ER 1000000
#define EPS_BN 1e-5f

// ---------------- workspace layout (float offsets unless noted) ----------------
// A: ssum_soc -> t_u        [NU*64]
// degs: soc, ru, v          [50K each]
// C: ssum_ru  -> t_v        [NU*64]
// D: ssum_v   -> x_u        [NV*64]
// E: h_u      -> x_v        [NU*64]
// F: h_v                    [NV*64]
// wcomb: Wself0+Wself2 (4096) + bias (64)
// stats: 8 arrays           [464]
// bnp: scale/shift x4       [416]
// y1 (bf16): byte offset 64,640,000  size 128MB
// y2 (bf16): byte offset 192,640,000 size 32MB
static const size_t OFF_A       = 0;
static const size_t OFF_DEG_SOC = 3200000;
static const size_t OFF_DEG_RU  = 3250000;
static const size_t OFF_DEG_V   = 3300000;
static const size_t OFF_C       = 3350000;
static const size_t OFF_D       = 6550000;
static const size_t OFF_E       = 9750000;
static const size_t OFF_F       = 12950000;
static const size_t OFF_WCOMB   = 16150000;
static const size_t OFF_STATS   = 16154160;
static const size_t OFF_BNP     = 16154624;
static const size_t OFF_Y1_BYTES = 64640000;   // after 16,160,000 floats
static const size_t OFF_Y2_BYTES = 192640000;

// ---------------- helpers ----------------
__device__ __forceinline__ unsigned short f2bf(float f) {
  unsigned u = __float_as_uint(f);
  unsigned r = u + 0x7FFF + ((u >> 16) & 1);   // RNE (finite values)
  return (unsigned short)(r >> 16);
}
__device__ __forceinline__ float bf2f(unsigned short h) {
  return __uint_as_float(((unsigned)h) << 16);
}

// acc[j] (float4, 16 of them = 64 cols) += xk * Wrow[0..63]
__device__ __forceinline__ void fma_row(float xk, const float* __restrict__ wrow, float4* acc) {
  const float4* w = (const float4*)wrow;
#pragma unroll
  for (int j = 0; j < 16; ++j) {
    float4 wv = w[j];
    acc[j].x = fmaf(xk, wv.x, acc[j].x);
    acc[j].y = fmaf(xk, wv.y, acc[j].y);
    acc[j].z = fmaf(xk, wv.z, acc[j].z);
    acc[j].w = fmaf(xk, wv.w, acc[j].w);
  }
}

// column sums + sumsq across the wave for C columns (C=64 -> nj=16, C=16 -> nj=4)
template <int NJ>
__device__ __forceinline__ void col_stats(const float4* acc, bool valid,
                                          float* __restrict__ ssum, float* __restrict__ ssq) {
#pragma unroll
  for (int j = 0; j < NJ; ++j) {
#pragma unroll
    for (int c = 0; c < 4; ++c) {
      float v = valid ? (&acc[j].x)[c] : 0.0f;
      float s = v, q = v * v;
#pragma unroll
      for (int off = 32; off >= 1; off >>= 1) {
        s += __shfl_down(s, off, 64);
        q += __shfl_down(q, off, 64);
      }
      if ((threadIdx.x & 63) == 0) {
        atomicAdd(&ssum[j * 4 + c], s);
        atomicAdd(&ssq[j * 4 + c], q);
      }
    }
  }
}

// ---------------- kernels ----------------
__global__ __launch_bounds__(256) void wcomb_kernel(const float* __restrict__ W_self,
                                                    const float* __restrict__ b_self,
                                                    float* __restrict__ wcomb) {
  int i = blockIdx.x * 256 + threadIdx.x;
  if (i < 4096) wcomb[i] = W_self[i] + W_self[8192 + i];
  if (i < 64) wcomb[4096 + i] = b_self[i] + b_self[128 + i];
}

// generic: ssum[dst] += tab[src], deg[dst] += 1  (wave per edge, lane = column)
__global__ __launch_bounds__(256) void agg_kernel(const float* __restrict__ tab,
                                                  const int* __restrict__ src_idx,
                                                  const int* __restrict__ dst_idx, int E,
                                                  float* __restrict__ ssum,
                                                  float* __restrict__ deg) {
  int wave = (blockIdx.x * 256 + threadIdx.x) >> 6;
  int lane = threadIdx.x & 63;
  if (wave >= E) return;
  int s = src_idx[wave];
  int d = dst_idx[wave];
  atomicAdd(&ssum[(size_t)d * 64 + lane], tab[(size_t)s * 64 + lane]);
  if (lane == 0) atomicAdd(&deg[d], 1.0f);
}

// both rates-edge aggregations in one pass
__global__ __launch_bounds__(256) void agg_rates_kernel(const float* __restrict__ u2e,
                                                        const float* __restrict__ v2e,
                                                        const int* __restrict__ rs,
                                                        const int* __restrict__ rd,
                                                        float* __restrict__ ssum_ru,
                                                        float* __restrict__ deg_ru,
                                                        float* __restrict__ ssum_v,
                                                        float* __restrict__ deg_v) {
  int wave = (blockIdx.x * 256 + threadIdx.x) >> 6;
  int lane = threadIdx.x & 63;
  if (wave >= ER) return;
  int s = rs[wave];   // user
  int d = rd[wave];   // item
  atomicAdd(&ssum_ru[(size_t)s * 64 + lane], v2e[(size_t)d * 64 + lane]);
  atomicAdd(&ssum_v[(size_t)d * 64 + lane], u2e[(size_t)s * 64 + lane]);
  if (lane == 0) { atomicAdd(&deg_ru[s], 1.0f); atomicAdd(&deg_v[d], 1.0f); }
}

// h_u = u2e@Wcomb + bcomb + (ssum_soc/deg)@Wn0 + (ssum_ru/deg)@Wn2
__global__ __launch_bounds__(256) void hu_kernel(const float* __restrict__ u2e,
                                                 const float* __restrict__ wcomb,
                                                 const float* __restrict__ W_neigh,
                                                 const float* __restrict__ ssum_soc,
                                                 const float* __restrict__ deg_soc,
                                                 const float* __restrict__ ssum_ru,
                                                 const float* __restrict__ deg_ru,
                                                 float* __restrict__ h_u) {
  __shared__ float Wc[4096], W0[4096], W2[4096], bc[64];
  for (int i = threadIdx.x; i < 4096; i += 256) {
    Wc[i] = wcomb[i];
    W0[i] = W_neigh[i];
    W2[i] = W_neigh[8192 + i];
  }
  if (threadIdx.x < 64) bc[threadIdx.x] = wcomb[4096 + threadIdx.x];
  __syncthreads();
  int row = blockIdx.x * 256 + threadIdx.x;
  if (row >= NU) return;
  float4 acc[16];
#pragma unroll
  for (int j = 0; j < 16; ++j) acc[j] = ((const float4*)bc)[j];
  const float4* xr = (const float4*)&u2e[(size_t)row * 64];
  const float4* n0 = (const float4*)&ssum_soc[(size_t)row * 64];
  const float4* n2 = (const float4*)&ssum_ru[(size_t)row * 64];
  float inv0 = 1.0f / fmaxf(deg_soc[row], 1.0f);
  float inv2 = 1.0f / fmaxf(deg_ru[row], 1.0f);
#pragma unroll 1
  for (int k4 = 0; k4 < 16; ++k4) {
    float4 a = xr[k4], b0 = n0[k4], b2 = n2[k4];
#pragma unroll
    for (int kk = 0; kk < 4; ++kk) {
      int k = k4 * 4 + kk;
      fma_row((&a.x)[kk], &Wc[k * 64], acc);
      fma_row((&b0.x)[kk] * inv0, &W0[k * 64], acc);
      fma_row((&b2.x)[kk] * inv2, &W2[k * 64], acc);
    }
  }
  float4* o = (float4*)&h_u[(size_t)row * 64];
#pragma unroll
  for (int j = 0; j < 16; ++j) o[j] = acc[j];
}

// h_v = v2e@Wself1 + bself1 + (ssum_v/deg)@Wn1
__global__ __launch_bounds__(256) void hv_kernel(const float* __restrict__ v2e,
                                                 const float* __restrict__ W_self,
                                                 const float* __restrict__ b_self,
                                                 const float* __restrict__ W_neigh,
                                                 const float* __restrict__ ssum_v,
                                                 const float* __restrict__ deg_v,
                                                 float* __restrict__ h_v) {
  __shared__ float Ws[4096], Wn[4096], bl[64];
  for (int i = threadIdx.x; i < 4096; i += 256) {
    Ws[i] = W_self[4096 + i];
    Wn[i] = W_neigh[4096 + i];
  }
  if (threadIdx.x < 64) bl[threadIdx.x] = b_self[64 + threadIdx.x];
  __syncthreads();
  int row = blockIdx.x * 256 + threadIdx.x;
  if (row >= NV) return;
  float4 acc[16];
#pragma unroll
  for (int j = 0; j < 16; ++j) acc[j] = ((const float4*)bl)[j];
  const float4* xr = (const float4*)&v2e[(size_t)row * 64];
  const float4* nv = (const float4*)&ssum_v[(size_t)row * 64];
  float inv = 1.0f / fmaxf(deg_v[row], 1.0f);
#pragma unroll 1
  for (int k4 = 0; k4 < 16; ++k4) {
    float4 a = xr[k4], b0 = nv[k4];
#pragma unroll
    for (int kk = 0; kk < 4; ++kk) {
      int k = k4 * 4 + kk;
      fma_row((&a.x)[kk], &Ws[k * 64], acc);
      fma_row((&b0.x)[kk] * inv, &Wn[k * 64], acc);
    }
  }
  float4* o = (float4*)&h_v[(size_t)row * 64];
#pragma unroll
  for (int j = 0; j < 16; ++j) o[j] = acc[j];
}

// out = in@W + b ; accumulate column sum/sumsq
__global__ __launch_bounds__(256) void lin_stats_kernel(const float* __restrict__ in,
                                                        const float* __restrict__ W,
                                                        const float* __restrict__ b, int N,
                                                        float* __restrict__ out,
                                                        float* __restrict__ ssum,
                                                        float* __restrict__ ssq) {
  __shared__ float Wl[4096], bl[64];
  for (int i = threadIdx.x; i < 4096; i += 256) Wl[i] = W[i];
  if (threadIdx.x < 64) bl[threadIdx.x] = b[threadIdx.x];
  __syncthreads();
  int row = blockIdx.x * 256 + threadIdx.x;
  bool valid = row < N;
  float4 acc[16];
#pragma unroll
  for (int j = 0; j < 16; ++j) acc[j] = ((const float4*)bl)[j];
  if (valid) {
    const float4* xr = (const float4*)&in[(size_t)row * 64];
#pragma unroll 1
    for (int k4 = 0; k4 < 16; ++k4) {
      float4 a = xr[k4];
#pragma unroll
      for (int kk = 0; kk < 4; ++kk) fma_row((&a.x)[kk], &Wl[(k4 * 4 + kk) * 64], acc);
    }
    float4* o = (float4*)&out[(size_t)row * 64];
#pragma unroll
    for (int j = 0; j < 16; ++j) o[j] = acc[j];
  }
  col_stats<16>(acc, valid, ssum, ssq);
}

// scale/shift from stats
__global__ void bn_final_kernel(const float* __restrict__ ssum, const float* __restrict__ ssq,
                                const float* __restrict__ gamma, const float* __restrict__ beta,
                                float n, int C, float* __restrict__ bnp) {
  int j = threadIdx.x;
  if (j >= C) return;
  float m = ssum[j] / n;
  float var = ssq[j] / n - m * m;
  float s = gamma[j] * rsqrtf(var + EPS_BN);
  bnp[j] = s;
  bnp[C + j] = beta[j] - m * s;
}

// x = relu(t*scale+shift) @ W2 + b2
__global__ __launch_bounds__(256) void bnrelu_lin_kernel(const float* __restrict__ tin,
                                                         const float* __restrict__ bnp,
                                                         const float* __restrict__ W,
                                                         const float* __restrict__ b, int N,
                                                         float* __restrict__ xout) {
  __shared__ float Wl[4096], bl[64], sc[64], sh[64];
  for (int i = threadIdx.x; i < 4096; i += 256) Wl[i] = W[i];
  if (threadIdx.x < 64) {
    bl[threadIdx.x] = b[threadIdx.x];
    sc[threadIdx.x] = bnp[threadIdx.x];
    sh[threadIdx.x] = bnp[64 + threadIdx.x];
  }
  __syncthreads();
  int row = blockIdx.x * 256 + threadIdx.x;
  if (row >= N) return;
  float4 acc[16];
#pragma unroll
  for (int j = 0; j < 16; ++j) acc[j] = ((const float4*)bl)[j];
  const float4* xr = (const float4*)&tin[(size_t)row * 64];
#pragma unroll 1
  for (int k4 = 0; k4 < 16; ++k4) {
    float4 a = xr[k4];
#pragma unroll
    for (int kk = 0; kk < 4; ++kk) {
      int k = k4 * 4 + kk;
      float z = fmaxf(fmaf((&a.x)[kk], sc[k], sh[k]), 0.0f);
      fma_row(z, &Wl[k * 64], acc);
    }
  }
  float4* o = (float4*)&xout[(size_t)row * 64];
#pragma unroll
  for (int j = 0; j < 16; ++j) o[j] = acc[j];
}

// y1 = (x_u[rs] * x_v[rd]) @ Wuv1 + buv1 (store bf16) ; stats
__global__ __launch_bounds__(256) void e1_kernel(const float* __restrict__ xu,
                                                 const float* __restrict__ xv,
                                                 const int* __restrict__ rs,
                                                 const int* __restrict__ rd,
                                                 const float* __restrict__ W,
                                                 const float* __restrict__ b,
                                                 unsigned short* __restrict__ y1,
                                                 float* __restrict__ ssum,
                                                 float* __restrict__ ssq) {
  __shared__ float Wl[4096], bl[64];
  for (int i = threadIdx.x; i < 4096; i += 256) Wl[i] = W[i];
  if (threadIdx.x < 64) bl[threadIdx.x] = b[threadIdx.x];
  __syncthreads();
  int e = blockIdx.x * 256 + threadIdx.x;
  bool valid = e < ER;
  float4 acc[16];
#pragma unroll
  for (int j = 0; j < 16; ++j) acc[j] = ((const float4*)bl)[j];
  if (valid) {
    int a = rs[e], bi = rd[e];
    const float4* xa = (const float4*)&xu[(size_t)a * 64];
    const float4* xb = (const float4*)&xv[(size_t)bi * 64];
#pragma unroll 1
    for (int k4 = 0; k4 < 16; ++k4) {
      float4 va = xa[k4], vb = xb[k4];
      float p[4] = {va.x * vb.x, va.y * vb.y, va.z * vb.z, va.w * vb.w};
#pragma unroll
      for (int kk = 0; kk < 4; ++kk) fma_row(p[kk], &Wl[(k4 * 4 + kk) * 64], acc);
    }
    ushort4* o = (ushort4*)&y1[(size_t)e * 64];
#pragma unroll
    for (int j = 0; j < 16; ++j) {
      ushort4 pk;
      pk.x = f2bf(acc[j].x); pk.y = f2bf(acc[j].y);
      pk.z = f2bf(acc[j].z); pk.w = f2bf(acc[j].w);
      o[j] = pk;
    }
  }
  col_stats<16>(acc, valid, ssum, ssq);
}

// y2 = relu(y1*sc+sh) @ Wuv2 + buv2 (store bf16) ; stats (16 cols)
__global__ __launch_bounds__(256) void e2_kernel(const unsigned short* __restrict__ y1,
                                                 const float* __restrict__ bnp3,
                                                 const float* __restrict__ W,  // [64,16]
                                                 const float* __restrict__ b,  // [16]
                                                 unsigned short* __restrict__ y2,
                                                 float* __restrict__ ssum,
                                                 float* __restrict__ ssq) {
  __shared__ float Wl[1024], bl[16], sc[64], sh[64];
  for (int i = threadIdx.x; i < 1024; i += 256) Wl[i] = W[i];
  if (threadIdx.x < 16) bl[threadIdx.x] = b[threadIdx.x];
  if (threadIdx.x < 64) { sc[threadIdx.x] = bnp3[threadIdx.x]; sh[threadIdx.x] = bnp3[64 + threadIdx.x]; }
  __syncthreads();
  int e = blockIdx.x * 256 + threadIdx.x;
  bool valid = e < ER;
  float4 acc[4];
#pragma unroll
  for (int j = 0; j < 4; ++j) acc[j] = ((const float4*)bl)[j];
  if (valid) {
    const ushort4* yr = (const ushort4*)&y1[(size_t)e * 64];
#pragma unroll 1
    for (int k4 = 0; k4 < 16; ++k4) {
      ushort4 v = yr[k4];
      float vf[4] = {bf2f(v.x), bf2f(v.y), bf2f(v.z), bf2f(v.w)};
#pragma unroll
      for (int kk = 0; kk < 4; ++kk) {
        int k = k4 * 4 + kk;
        float z = fmaxf(fmaf(vf[kk], sc[k], sh[k]), 0.0f);
        const float4* w = (const float4*)&Wl[k * 16];
#pragma unroll
        for (int j = 0; j < 4; ++j) {
          float4 wv = w[j];
          acc[j].x = fmaf(z, wv.x, acc[j].x);
          acc[j].y = fmaf(z, wv.y, acc[j].y);
          acc[j].z = fmaf(z, wv.z, acc[j].z);
          acc[j].w = fmaf(z, wv.w, acc[j].w);
        }
      }
    }
    ushort4* o = (ushort4*)&y2[(size_t)e * 16];
#pragma unroll
    for (int j = 0; j < 4; ++j) {
      ushort4 pk;
      pk.x = f2bf(acc[j].x); pk.y = f2bf(acc[j].y);
      pk.z = f2bf(acc[j].z); pk.w = f2bf(acc[j].w);
      o[j] = pk;
    }
  }
  col_stats<4>(acc, valid, ssum, ssq);
}

// scores = relu(y2*sc+sh) . w3 + b3
__global__ __launch_bounds__(256) void e3_kernel(const unsigned short* __restrict__ y2,
                                                 const float* __restrict__ bnp4,
                                                 const float* __restrict__ w3,
                                                 const float* __restrict__ b3,
                                                 float* __restrict__ out) {
  __shared__ float sc[16], sh[16], wl[16];
  if (threadIdx.x < 16) {
    sc[threadIdx.x] = bnp4[threadIdx.x];
    sh[threadIdx.x] = bnp4[16 + threadIdx.x];
    wl[threadIdx.x] = w3[threadIdx.x];
  }
  __syncthreads();
  int e = blockIdx.x * 256 + threadIdx.x;
  if (e >= ER) return;
  const ushort4* yr = (const ushort4*)&y2[(size_t)e * 16];
  float acc = b3[0];
#pragma unroll
  for (int k4 = 0; k4 < 4; ++k4) {
    ushort4 v = yr[k4];
    float vf[4] = {bf2f(v.x), bf2f(v.y), bf2f(v.z), bf2f(v.w)};
#pragma unroll
    for (int kk = 0; kk < 4; ++kk) {
      int k = k4 * 4 + kk;
      float z = fmaxf(fmaf(vf[kk], sc[k], sh[k]), 0.0f);
      acc = fmaf(z, wl[k], acc);
    }
  }
  out[e] = acc;
}

// ---------------- host ----------------
extern "C" void kernel_launch(void* const* d_in, const int* in_sizes, int n_in,
                              void* d_out, int out_size, void* d_ws, size_t ws_size,
                              hipStream_t stream) {
  const float* u2e = (const float*)d_in[0];
  const float* v2e = (const float*)d_in[1];
  const float* W_self = (const float*)d_in[2];
  const float* b_self = (const float*)d_in[3];
  const float* W_neigh = (const float*)d_in[4];
  const float* Wur1 = (const float*)d_in[5];
  const float* bur1 = (const float*)d_in[6];
  const float* Wur2 = (const float*)d_in[7];
  const float* bur2 = (const float*)d_in[8];
  const float* Wvr1 = (const float*)d_in[9];
  const float* bvr1 = (const float*)d_in[10];
  const float* Wvr2 = (const float*)d_in[11];
  const float* bvr2 = (const float*)d_in[12];
  const float* Wuv1 = (const float*)d_in[13];
  const float* buv1 = (const float*)d_in[14];
  const float* Wuv2 = (const float*)d_in[15];
  const float* buv2 = (const float*)d_in[16];
  const float* Wuv3 = (const float*)d_in[17];
  const float* buv3 = (const float*)d_in[18];
  const float* bn_gamma = (const float*)d_in[19];
  const float* bn_beta = (const float*)d_in[20];
  const float* bn4_gamma = (const float*)d_in[21];
  const float* bn4_beta = (const float*)d_in[22];
  const int* social_src = (const int*)d_in[23];
  const int* social_dst = (const int*)d_in[24];
  const int* rates_src = (const int*)d_in[25];
  const int* rates_dst = (const int*)d_in[26];
  float* out = (float*)d_out;
  float* ws = (float*)d_ws;

  float* A = ws + OFF_A;
  float* degS = ws + OFF_DEG_SOC;
  float* degR = ws + OFF_DEG_RU;
  float* degV = ws + OFF_DEG_V;
  float* Cb = ws + OFF_C;
  float* Db = ws + OFF_D;
  float* Eb = ws + OFF_E;
  float* Fb = ws + OFF_F;
  float* wcomb = ws + OFF_WCOMB;
  float* stats = ws + OFF_STATS;
  float* bnp = ws + OFF_BNP;
  unsigned short* y1 = (unsigned short*)((char*)d_ws + OFF_Y1_BYTES);
  unsigned short* y2 = (unsigned short*)((char*)d_ws + OFF_Y2_BYTES);

  // zero accumulators (A, degs, C, D are contiguous) + stats
  hipMemsetAsync(ws, 0, (size_t)9750000 * sizeof(float), stream);
  hipMemsetAsync(stats, 0, 464 * sizeof(float), stream);

  wcomb_kernel<<<16, 256, 0, stream>>>(W_self, b_self, wcomb);

  agg_kernel<<<ES / 4, 256, 0, stream>>>(u2e, social_src, social_dst, ES, A, degS);
  agg_rates_kernel<<<ER / 4, 256, 0, stream>>>(u2e, v2e, rates_src, rates_dst, Cb, degR, Db, degV);

  hu_kernel<<<(NU + 255) / 256, 256, 0, stream>>>(u2e, wcomb, W_neigh, A, degS, Cb, degR, Eb);
  hv_kernel<<<(NV + 255) / 256, 256, 0, stream>>>(v2e, W_self, b_self, W_neigh, Db, degV, Fb);

  lin_stats_kernel<<<(NU + 255) / 256, 256, 0, stream>>>(Eb, Wur1, bur1, NU, A, stats + 0, stats + 64);
  lin_stats_kernel<<<(NV + 255) / 256, 256, 0, stream>>>(Fb, Wvr1, bvr1, NV, Cb, stats + 128, stats + 192);

  bn_final_kernel<<<1, 64, 0, stream>>>(stats + 0, stats + 64, bn_gamma, bn_beta, (float)NU, 64, bnp);
  bn_final_kernel<<<1, 64, 0, stream>>>(stats + 128, stats + 192, bn_gamma + 64, bn_beta + 64, (float)NV, 64, bnp + 128);

  bnrelu_lin_kernel<<<(NU + 255) / 256, 256, 0, stream>>>(A, bnp, Wur2, bur2, NU, Db);
  bnrelu_lin_kernel<<<(NV + 255) / 256, 256, 0, stream>>>(Cb, bnp + 128, Wvr2, bvr2, NV, Eb);

  e1_kernel<<<(ER + 255) / 256, 256, 0, stream>>>(Db, Eb, rates_src, rates_dst, Wuv1, buv1, y1,
                                                  stats + 256, stats + 320);
  bn_final_kernel<<<1, 64, 0, stream>>>(stats + 256, stats + 320, bn_gamma + 128, bn_beta + 128,
                                        (float)ER, 64, bnp + 256);
  e2_kernel<<<(ER + 255) / 256, 256, 0, stream>>>(y1, bnp + 256, Wuv2, buv2, y2,
                                                  stats + 384, stats + 400);
  bn_final_kernel<<<1, 16, 0, stream>>>(stats + 384, stats + 400, bn4_gamma, bn4_beta,
                                        (float)ER, 16, bnp + 384);
  e3_kernel<<<(ER + 255) / 256, 256, 0, stream>>>(y2, bnp + 384, Wuv3, buv3, out);
}

// Round 2
// 2570.990 us; speedup vs baseline: 4.4074x; 4.4074x over previous
//
#include <hip/hip_runtime.h>

#define NU 50000
#define NV 50000
#define ES 800000
#define ER 1000000
#define EPS_BN 1e-5f

// ---------------- workspace layout (float offsets unless noted) ----------------
static const size_t OFF_A       = 0;
static const size_t OFF_DEG_SOC = 3200000;
static const size_t OFF_DEG_RU  = 3250000;
static const size_t OFF_DEG_V   = 3300000;
static const size_t OFF_C       = 3350000;
static const size_t OFF_D       = 6550000;
static const size_t OFF_E       = 9750000;
static const size_t OFF_F       = 12950000;
static const size_t OFF_WCOMB   = 16150000;
static const size_t OFF_STATS   = 16154160;
static const size_t OFF_BNP     = 16154624;
static const size_t OFF_Y1_BYTES = 64640000;
static const size_t OFF_Y2_BYTES = 192640000;

// ---------------- helpers ----------------
__device__ __forceinline__ unsigned short f2bf(float f) {
  unsigned u = __float_as_uint(f);
  unsigned r = u + 0x7FFF + ((u >> 16) & 1);   // RNE (finite values)
  return (unsigned short)(r >> 16);
}
__device__ __forceinline__ float bf2f(unsigned short h) {
  return __uint_as_float(((unsigned)h) << 16);
}

__device__ __forceinline__ void fma_row(float xk, const float* __restrict__ wrow, float4* acc) {
  const float4* w = (const float4*)wrow;
#pragma unroll
  for (int j = 0; j < 16; ++j) {
    float4 wv = w[j];
    acc[j].x = fmaf(xk, wv.x, acc[j].x);
    acc[j].y = fmaf(xk, wv.y, acc[j].y);
    acc[j].z = fmaf(xk, wv.z, acc[j].z);
    acc[j].w = fmaf(xk, wv.w, acc[j].w);
  }
}

template <int NJ>
__device__ __forceinline__ void col_stats(const float4* acc, bool valid,
                                          float* __restrict__ ssum, float* __restrict__ ssq) {
#pragma unroll
  for (int j = 0; j < NJ; ++j) {
#pragma unroll
    for (int c = 0; c < 4; ++c) {
      float v = valid ? (&acc[j].x)[c] : 0.0f;
      float s = v, q = v * v;
#pragma unroll
      for (int off = 32; off >= 1; off >>= 1) {
        s += __shfl_down(s, off, 64);
        q += __shfl_down(q, off, 64);
      }
      if ((threadIdx.x & 63) == 0) {
        atomicAdd(&ssum[j * 4 + c], s);
        atomicAdd(&ssq[j * 4 + c], q);
      }
    }
  }
}

// ---------------- kernels ----------------
__global__ __launch_bounds__(256) void wcomb_kernel(const float* __restrict__ W_self,
                                                    const float* __restrict__ b_self,
                                                    float* __restrict__ wcomb) {
  int i = blockIdx.x * 256 + threadIdx.x;
  if (i < 4096) wcomb[i] = W_self[i] + W_self[8192 + i];
  if (i < 64) wcomb[4096 + i] = b_self[i] + b_self[128 + i];
}

__global__ __launch_bounds__(256) void agg_kernel(const float* __restrict__ tab,
                                                  const int* __restrict__ src_idx,
                                                  const int* __restrict__ dst_idx, int E,
                                                  float* __restrict__ ssum,
                                                  float* __restrict__ deg) {
  int wave = (blockIdx.x * 256 + threadIdx.x) >> 6;
  int lane = threadIdx.x & 63;
  if (wave >= E) return;
  int s = src_idx[wave];
  int d = dst_idx[wave];
  atomicAdd(&ssum[(size_t)d * 64 + lane], tab[(size_t)s * 64 + lane]);
  if (lane == 0) atomicAdd(&deg[d], 1.0f);
}

__global__ __launch_bounds__(256) void agg_rates_kernel(const float* __restrict__ u2e,
                                                        const float* __restrict__ v2e,
                                                        const int* __restrict__ rs,
                                                        const int* __restrict__ rd,
                                                        float* __restrict__ ssum_ru,
                                                        float* __restrict__ deg_ru,
                                                        float* __restrict__ ssum_v,
                                                        float* __restrict__ deg_v) {
  int wave = (blockIdx.x * 256 + threadIdx.x) >> 6;
  int lane = threadIdx.x & 63;
  if (wave >= ER) return;
  int s = rs[wave];   // user
  int d = rd[wave];   // item
  atomicAdd(&ssum_ru[(size_t)s * 64 + lane], v2e[(size_t)d * 64 + lane]);
  atomicAdd(&ssum_v[(size_t)d * 64 + lane], u2e[(size_t)s * 64 + lane]);
  if (lane == 0) { atomicAdd(&deg_ru[s], 1.0f); atomicAdd(&deg_v[d], 1.0f); }
}

__global__ __launch_bounds__(256) void hu_kernel(const float* __restrict__ u2e,
                                                 const float* __restrict__ wcomb,
                                                 const float* __restrict__ W_neigh,
                                                 const float* __restrict__ ssum_soc,
                                                 const float* __restrict__ deg_soc,
                                                 const float* __restrict__ ssum_ru,
                                                 const float* __restrict__ deg_ru,
                                                 float* __restrict__ h_u) {
  __shared__ float Wc[4096], W0[4096], W2[4096], bc[64];
  for (int i = threadIdx.x; i < 4096; i += 256) {
    Wc[i] = wcomb[i];
    W0[i] = W_neigh[i];
    W2[i] = W_neigh[8192 + i];
  }
  if (threadIdx.x < 64) bc[threadIdx.x] = wcomb[4096 + threadIdx.x];
  __syncthreads();
  int row = blockIdx.x * 256 + threadIdx.x;
  if (row >= NU) return;
  float4 acc[16];
#pragma unroll
  for (int j = 0; j < 16; ++j) acc[j] = ((const float4*)bc)[j];
  const float4* xr = (const float4*)&u2e[(size_t)row * 64];
  const float4* n0 = (const float4*)&ssum_soc[(size_t)row * 64];
  const float4* n2 = (const float4*)&ssum_ru[(size_t)row * 64];
  float inv0 = 1.0f / fmaxf(deg_soc[row], 1.0f);
  float inv2 = 1.0f / fmaxf(deg_ru[row], 1.0f);
#pragma unroll 1
  for (int k4 = 0; k4 < 16; ++k4) {
    float4 a = xr[k4], b0 = n0[k4], b2 = n2[k4];
#pragma unroll
    for (int kk = 0; kk < 4; ++kk) {
      int k = k4 * 4 + kk;
      fma_row((&a.x)[kk], &Wc[k * 64], acc);
      fma_row((&b0.x)[kk] * inv0, &W0[k * 64], acc);
      fma_row((&b2.x)[kk] * inv2, &W2[k * 64], acc);
    }
  }
  float4* o = (float4*)&h_u[(size_t)row * 64];
#pragma unroll
  for (int j = 0; j < 16; ++j) o[j] = acc[j];
}

__global__ __launch_bounds__(256) void hv_kernel(const float* __restrict__ v2e,
                                                 const float* __restrict__ W_self,
                                                 const float* __restrict__ b_self,
                                                 const float* __restrict__ W_neigh,
                                                 const float* __restrict__ ssum_v,
                                                 const float* __restrict__ deg_v,
                                                 float* __restrict__ h_v) {
  __shared__ float Ws[4096], Wn[4096], bl[64];
  for (int i = threadIdx.x; i < 4096; i += 256) {
    Ws[i] = W_self[4096 + i];
    Wn[i] = W_neigh[4096 + i];
  }
  if (threadIdx.x < 64) bl[threadIdx.x] = b_self[64 + threadIdx.x];
  __syncthreads();
  int row = blockIdx.x * 256 + threadIdx.x;
  if (row >= NV) return;
  float4 acc[16];
#pragma unroll
  for (int j = 0; j < 16; ++j) acc[j] = ((const float4*)bl)[j];
  const float4* xr = (const float4*)&v2e[(size_t)row * 64];
  const float4* nv = (const float4*)&ssum_v[(size_t)row * 64];
  float inv = 1.0f / fmaxf(deg_v[row], 1.0f);
#pragma unroll 1
  for (int k4 = 0; k4 < 16; ++k4) {
    float4 a = xr[k4], b0 = nv[k4];
#pragma unroll
    for (int kk = 0; kk < 4; ++kk) {
      int k = k4 * 4 + kk;
      fma_row((&a.x)[kk], &Ws[k * 64], acc);
      fma_row((&b0.x)[kk] * inv, &Wn[k * 64], acc);
    }
  }
  float4* o = (float4*)&h_v[(size_t)row * 64];
#pragma unroll
  for (int j = 0; j < 16; ++j) o[j] = acc[j];
}

__global__ __launch_bounds__(256) void lin_stats_kernel(const float* __restrict__ in,
                                                        const float* __restrict__ W,
                                                        const float* __restrict__ b, int N,
                                                        float* __restrict__ out,
                                                        float* __restrict__ ssum,
                                                        float* __restrict__ ssq) {
  __shared__ float Wl[4096], bl[64];
  for (int i = threadIdx.x; i < 4096; i += 256) Wl[i] = W[i];
  if (threadIdx.x < 64) bl[threadIdx.x] = b[threadIdx.x];
  __syncthreads();
  int row = blockIdx.x * 256 + threadIdx.x;
  bool valid = row < N;
  float4 acc[16];
#pragma unroll
  for (int j = 0; j < 16; ++j) acc[j] = ((const float4*)bl)[j];
  if (valid) {
    const float4* xr = (const float4*)&in[(size_t)row * 64];
#pragma unroll 1
    for (int k4 = 0; k4 < 16; ++k4) {
      float4 a = xr[k4];
#pragma unroll
      for (int kk = 0; kk < 4; ++kk) fma_row((&a.x)[kk], &Wl[(k4 * 4 + kk) * 64], acc);
    }
    float4* o = (float4*)&out[(size_t)row * 64];
#pragma unroll
    for (int j = 0; j < 16; ++j) o[j] = acc[j];
  }
  col_stats<16>(acc, valid, ssum, ssq);
}

__global__ void bn_final_kernel(const float* __restrict__ ssum, const float* __restrict__ ssq,
                                const float* __restrict__ gamma, const float* __restrict__ beta,
                                float n, int C, float* __restrict__ bnp) {
  int j = threadIdx.x;
  if (j >= C) return;
  float m = ssum[j] / n;
  float var = ssq[j] / n - m * m;
  float s = gamma[j] * rsqrtf(var + EPS_BN);
  bnp[j] = s;
  bnp[C + j] = beta[j] - m * s;
}

__global__ __launch_bounds__(256) void bnrelu_lin_kernel(const float* __restrict__ tin,
                                                         const float* __restrict__ bnp,
                                                         const float* __restrict__ W,
                                                         const float* __restrict__ b, int N,
                                                         float* __restrict__ xout) {
  __shared__ float Wl[4096], bl[64], sc[64], sh[64];
  for (int i = threadIdx.x; i < 4096; i += 256) Wl[i] = W[i];
  if (threadIdx.x < 64) {
    bl[threadIdx.x] = b[threadIdx.x];
    sc[threadIdx.x] = bnp[threadIdx.x];
    sh[threadIdx.x] = bnp[64 + threadIdx.x];
  }
  __syncthreads();
  int row = blockIdx.x * 256 + threadIdx.x;
  if (row >= N) return;
  float4 acc[16];
#pragma unroll
  for (int j = 0; j < 16; ++j) acc[j] = ((const float4*)bl)[j];
  const float4* xr = (const float4*)&tin[(size_t)row * 64];
#pragma unroll 1
  for (int k4 = 0; k4 < 16; ++k4) {
    float4 a = xr[k4];
#pragma unroll
    for (int kk = 0; kk < 4; ++kk) {
      int k = k4 * 4 + kk;
      float z = fmaxf(fmaf((&a.x)[kk], sc[k], sh[k]), 0.0f);
      fma_row(z, &Wl[k * 64], acc);
    }
  }
  float4* o = (float4*)&xout[(size_t)row * 64];
#pragma unroll
  for (int j = 0; j < 16; ++j) o[j] = acc[j];
}

// ---- e1: wave-per-edge. lane = output column j. W column j kept in 64 VGPRs.
// p_d broadcast via readlane. Coalesced 256B gathers, coalesced 128B y1 write.
__global__ __launch_bounds__(256) void e1_kernel(const float* __restrict__ xu,
                                                 const float* __restrict__ xv,
                                                 const int* __restrict__ rs,
                                                 const int* __restrict__ rd,
                                                 const float* __restrict__ W,
                                                 const float* __restrict__ b,
                                                 unsigned short* __restrict__ y1,
                                                 float* __restrict__ ssum,
                                                 float* __restrict__ ssq) {
  __shared__ float s1[64], s2[64];
  int lane = threadIdx.x & 63;
  if (threadIdx.x < 64) { s1[threadIdx.x] = 0.0f; s2[threadIdx.x] = 0.0f; }
  __syncthreads();
  float wreg[64];
#pragma unroll
  for (int k = 0; k < 64; ++k) wreg[k] = W[k * 64 + lane];
  float bl = b[lane];
  float ssl = 0.0f, sql = 0.0f;
  int nwaves = (gridDim.x * 256) >> 6;
  int wid = (blockIdx.x * 256 + threadIdx.x) >> 6;
  for (int e = wid; e < ER; e += nwaves) {
    int s = rs[e], d = rd[e];
    float p = xu[(size_t)s * 64 + lane] * xv[(size_t)d * 64 + lane];
    float a0 = bl, a1 = 0.0f;
#pragma unroll
    for (int k = 0; k < 32; ++k) {
      float pk0 = __uint_as_float(__builtin_amdgcn_readlane(__float_as_uint(p), k));
      float pk1 = __uint_as_float(__builtin_amdgcn_readlane(__float_as_uint(p), k + 32));
      a0 = fmaf(pk0, wreg[k], a0);
      a1 = fmaf(pk1, wreg[k + 32], a1);
    }
    float acc = a0 + a1;
    y1[(size_t)e * 64 + lane] = f2bf(acc);
    ssl += acc;
    sql = fmaf(acc, acc, sql);
  }
  atomicAdd(&s1[lane], ssl);
  atomicAdd(&s2[lane], sql);
  __syncthreads();
  if (threadIdx.x < 64) {
    atomicAdd(&ssum[threadIdx.x], s1[threadIdx.x]);
    atomicAdd(&ssq[threadIdx.x], s2[threadIdx.x]);
  }
}

// ---- e2: wave-per-edge. lane = d. 16 partials per lane, xor-16/32 fold then
// 4-stage split butterfly (static reg indices). Lane L (<16) ends with y2[e, L].
__global__ __launch_bounds__(256) void e2_kernel(const unsigned short* __restrict__ y1,
                                                 const float* __restrict__ bnp3,
                                                 const float* __restrict__ W,   // [64,16]
                                                 const float* __restrict__ b,   // [16]
                                                 unsigned short* __restrict__ y2,
                                                 float* __restrict__ ssum,
                                                 float* __restrict__ ssq) {
  __shared__ float s1[16], s2[16];
  int lane = threadIdx.x & 63;
  if (threadIdx.x < 16) { s1[threadIdx.x] = 0.0f; s2[threadIdx.x] = 0.0f; }
  __syncthreads();
  float w2r[16];
#pragma unroll
  for (int j = 0; j < 16; ++j) w2r[j] = W[lane * 16 + j];
  float sc = bnp3[lane], sh = bnp3[64 + lane];
  int j16 = lane & 15;
  float bj = b[j16];
  float ssl = 0.0f, sql = 0.0f;
  int nwaves = (gridDim.x * 256) >> 6;
  int wid = (blockIdx.x * 256 + threadIdx.x) >> 6;
  for (int e = wid; e < ER; e += nwaves) {
    float z = fmaxf(fmaf(bf2f(y1[(size_t)e * 64 + lane]), sc, sh), 0.0f);
    float p[16];
#pragma unroll
    for (int j = 0; j < 16; ++j) p[j] = z * w2r[j];
#pragma unroll
    for (int j = 0; j < 16; ++j) p[j] += __shfl_xor(p[j], 16, 64);
#pragma unroll
    for (int j = 0; j < 16; ++j) p[j] += __shfl_xor(p[j], 32, 64);
    {  // m=8, half=8
      bool hb = (lane & 8) != 0;
#pragma unroll
      for (int i = 0; i < 8; ++i) {
        float send = hb ? p[i] : p[i + 8];
        float r = __shfl_xor(send, 8, 64);
        p[i] = (hb ? p[i + 8] : p[i]) + r;
      }
    }
    {  // m=4, half=4
      bool hb = (lane & 4) != 0;
#pragma unroll
      for (int i = 0; i < 4; ++i) {
        float send = hb ? p[i] : p[i + 4];
        float r = __shfl_xor(send, 4, 64);
        p[i] = (hb ? p[i + 4] : p[i]) + r;
      }
    }
    {  // m=2, half=2
      bool hb = (lane & 2) != 0;
#pragma unroll
      for (int i = 0; i < 2; ++i) {
        float send = hb ? p[i] : p[i + 2];
        float r = __shfl_xor(send, 2, 64);
        p[i] = (hb ? p[i + 2] : p[i]) + r;
      }
    }
    {  // m=1, half=1
      bool hb = (lane & 1) != 0;
      float send = hb ? p[0] : p[1];
      float r = __shfl_xor(send, 1, 64);
      p[0] = (hb ? p[1] : p[0]) + r;
    }
    float val = p[0] + bj;   // lane L holds y2[e, L&15] (replicated over L>>4)
    if (lane < 16) y2[(size_t)e * 16 + j16] = f2bf(val);
    ssl += val;
    sql = fmaf(val, val, sql);
  }
  if (lane < 16) { atomicAdd(&s1[j16], ssl); atomicAdd(&s2[j16], sql); }
  __syncthreads();
  if (threadIdx.x < 16) {
    atomicAdd(&ssum[threadIdx.x], s1[threadIdx.x]);
    atomicAdd(&ssq[threadIdx.x], s2[threadIdx.x]);
  }
}

__global__ __launch_bounds__(256) void e3_kernel(const unsigned short* __restrict__ y2,
                                                 const float* __restrict__ bnp4,
                                                 const float* __restrict__ w3,
                                                 const float* __restrict__ b3,
                                                 float* __restrict__ out) {
  __shared__ float sc[16], sh[16], wl[16];
  if (threadIdx.x < 16) {
    sc[threadIdx.x] = bnp4[threadIdx.x];
    sh[threadIdx.x] = bnp4[16 + threadIdx.x];
    wl[threadIdx.x] = w3[threadIdx.x];
  }
  __syncthreads();
  int e = blockIdx.x * 256 + threadIdx.x;
  if (e >= ER) return;
  const ushort4* yr = (const ushort4*)&y2[(size_t)e * 16];
  float acc = b3[0];
#pragma unroll
  for (int k4 = 0; k4 < 4; ++k4) {
    ushort4 v = yr[k4];
    float vf[4] = {bf2f(v.x), bf2f(v.y), bf2f(v.z), bf2f(v.w)};
#pragma unroll
    for (int kk = 0; kk < 4; ++kk) {
      int k = k4 * 4 + kk;
      float z = fmaxf(fmaf(vf[kk], sc[k], sh[k]), 0.0f);
      acc = fmaf(z, wl[k], acc);
    }
  }
  out[e] = acc;
}

// ---------------- host ----------------
extern "C" void kernel_launch(void* const* d_in, const int* in_sizes, int n_in,
                              void* d_out, int out_size, void* d_ws, size_t ws_size,
                              hipStream_t stream) {
  const float* u2e = (const float*)d_in[0];
  const float* v2e = (const float*)d_in[1];
  const float* W_self = (const float*)d_in[2];
  const float* b_self = (const float*)d_in[3];
  const float* W_neigh = (const float*)d_in[4];
  const float* Wur1 = (const float*)d_in[5];
  const float* bur1 = (const float*)d_in[6];
  const float* Wur2 = (const float*)d_in[7];
  const float* bur2 = (const float*)d_in[8];
  const float* Wvr1 = (const float*)d_in[9];
  const float* bvr1 = (const float*)d_in[10];
  const float* Wvr2 = (const float*)d_in[11];
  const float* bvr2 = (const float*)d_in[12];
  const float* Wuv1 = (const float*)d_in[13];
  const float* buv1 = (const float*)d_in[14];
  const float* Wuv2 = (const float*)d_in[15];
  const float* buv2 = (const float*)d_in[16];
  const float* Wuv3 = (const float*)d_in[17];
  const float* buv3 = (const float*)d_in[18];
  const float* bn_gamma = (const float*)d_in[19];
  const float* bn_beta = (const float*)d_in[20];
  const float* bn4_gamma = (const float*)d_in[21];
  const float* bn4_beta = (const float*)d_in[22];
  const int* social_src = (const int*)d_in[23];
  const int* social_dst = (const int*)d_in[24];
  const int* rates_src = (const int*)d_in[25];
  const int* rates_dst = (const int*)d_in[26];
  float* out = (float*)d_out;
  float* ws = (float*)d_ws;

  float* A = ws + OFF_A;
  float* degS = ws + OFF_DEG_SOC;
  float* degR = ws + OFF_DEG_RU;
  float* degV = ws + OFF_DEG_V;
  float* Cb = ws + OFF_C;
  float* Db = ws + OFF_D;
  float* Eb = ws + OFF_E;
  float* Fb = ws + OFF_F;
  float* wcomb = ws + OFF_WCOMB;
  float* stats = ws + OFF_STATS;
  float* bnp = ws + OFF_BNP;
  unsigned short* y1 = (unsigned short*)((char*)d_ws + OFF_Y1_BYTES);
  unsigned short* y2 = (unsigned short*)((char*)d_ws + OFF_Y2_BYTES);

  hipMemsetAsync(ws, 0, (size_t)9750000 * sizeof(float), stream);
  hipMemsetAsync(stats, 0, 464 * sizeof(float), stream);

  wcomb_kernel<<<16, 256, 0, stream>>>(W_self, b_self, wcomb);

  agg_kernel<<<ES / 4, 256, 0, stream>>>(u2e, social_src, social_dst, ES, A, degS);
  agg_rates_kernel<<<ER / 4, 256, 0, stream>>>(u2e, v2e, rates_src, rates_dst, Cb, degR, Db, degV);

  hu_kernel<<<(NU + 255) / 256, 256, 0, stream>>>(u2e, wcomb, W_neigh, A, degS, Cb, degR, Eb);
  hv_kernel<<<(NV + 255) / 256, 256, 0, stream>>>(v2e, W_self, b_self, W_neigh, Db, degV, Fb);

  lin_stats_kernel<<<(NU + 255) / 256, 256, 0, stream>>>(Eb, Wur1, bur1, NU, A, stats + 0, stats + 64);
  lin_stats_kernel<<<(NV + 255) / 256, 256, 0, stream>>>(Fb, Wvr1, bvr1, NV, Cb, stats + 128, stats + 192);

  bn_final_kernel<<<1, 64, 0, stream>>>(stats + 0, stats + 64, bn_gamma, bn_beta, (float)NU, 64, bnp);
  bn_final_kernel<<<1, 64, 0, stream>>>(stats + 128, stats + 192, bn_gamma + 64, bn_beta + 64, (float)NV, 64, bnp + 128);

  bnrelu_lin_kernel<<<(NU + 255) / 256, 256, 0, stream>>>(A, bnp, Wur2, bur2, NU, Db);
  bnrelu_lin_kernel<<<(NV + 255) / 256, 256, 0, stream>>>(Cb, bnp + 128, Wvr2, bvr2, NV, Eb);

  e1_kernel<<<2048, 256, 0, stream>>>(Db, Eb, rates_src, rates_dst, Wuv1, buv1, y1,
                                      stats + 256, stats + 320);
  bn_final_kernel<<<1, 64, 0, stream>>>(stats + 256, stats + 320, bn_gamma + 128, bn_beta + 128,
                                        (float)ER, 64, bnp + 256);
  e2_kernel<<<2048, 256, 0, stream>>>(y1, bnp + 256, Wuv2, buv2, y2,
                                      stats + 384, stats + 400);
  bn_final_kernel<<<1, 16, 0, stream>>>(stats + 384, stats + 400, bn4_gamma, bn4_beta,
                                        (float)ER, 16, bnp + 384);
  e3_kernel<<<(ER + 255) / 256, 256, 0, stream>>>(y2, bnp + 384, Wuv3, buv3, out);
}

// Round 3
// 2197.092 us; speedup vs baseline: 5.1575x; 1.1702x over previous
//
#include <hip/hip_runtime.h>

#define NU 50000
#define NV 50000
#define ES 800000
#define ER 1000000
#define EPS_BN 1e-5f

// ---------------- workspace layout (float offsets unless noted) ----------------
static const size_t OFF_A       = 0;
static const size_t OFF_DEG_SOC = 3200000;
static const size_t OFF_DEG_RU  = 3250000;
static const size_t OFF_DEG_V   = 3300000;
static const size_t OFF_C       = 3350000;
static const size_t OFF_D       = 6550000;
static const size_t OFF_E       = 9750000;
static const size_t OFF_F       = 12950000;
static const size_t OFF_WCOMB   = 16150000;
static const size_t OFF_STATS   = 16154160;
static const size_t OFF_BNP     = 16154624;
static const size_t OFF_Y1_BYTES = 64640000;   // y1T: [64][ER] bf16, 128MB
static const size_t OFF_Y2_BYTES = 192640000;  // y2T: [16][ER] bf16, 32MB

// ---------------- helpers ----------------
__device__ __forceinline__ unsigned short f2bf(float f) {
  unsigned u = __float_as_uint(f);
  unsigned r = u + 0x7FFF + ((u >> 16) & 1);   // RNE (finite values)
  return (unsigned short)(r >> 16);
}
__device__ __forceinline__ float bf2f(unsigned short h) {
  return __uint_as_float(((unsigned)h) << 16);
}

__device__ __forceinline__ void fma_row(float xk, const float* __restrict__ wrow, float4* acc) {
  const float4* w = (const float4*)wrow;
#pragma unroll
  for (int j = 0; j < 16; ++j) {
    float4 wv = w[j];
    acc[j].x = fmaf(xk, wv.x, acc[j].x);
    acc[j].y = fmaf(xk, wv.y, acc[j].y);
    acc[j].z = fmaf(xk, wv.z, acc[j].z);
    acc[j].w = fmaf(xk, wv.w, acc[j].w);
  }
}

template <int NJ>
__device__ __forceinline__ void col_stats(const float4* acc, bool valid,
                                          float* __restrict__ ssum, float* __restrict__ ssq) {
#pragma unroll
  for (int j = 0; j < NJ; ++j) {
#pragma unroll
    for (int c = 0; c < 4; ++c) {
      float v = valid ? (&acc[j].x)[c] : 0.0f;
      float s = v, q = v * v;
#pragma unroll
      for (int off = 32; off >= 1; off >>= 1) {
        s += __shfl_down(s, off, 64);
        q += __shfl_down(q, off, 64);
      }
      if ((threadIdx.x & 63) == 0) {
        atomicAdd(&ssum[j * 4 + c], s);
        atomicAdd(&ssq[j * 4 + c], q);
      }
    }
  }
}

// ---------------- kernels ----------------
__global__ __launch_bounds__(256) void wcomb_kernel(const float* __restrict__ W_self,
                                                    const float* __restrict__ b_self,
                                                    float* __restrict__ wcomb) {
  int i = blockIdx.x * 256 + threadIdx.x;
  if (i < 4096) wcomb[i] = W_self[i] + W_self[8192 + i];
  if (i < 64) wcomb[4096 + i] = b_self[i] + b_self[128 + i];
}

__global__ __launch_bounds__(256) void agg_kernel(const float* __restrict__ tab,
                                                  const int* __restrict__ src_idx,
                                                  const int* __restrict__ dst_idx, int E,
                                                  float* __restrict__ ssum,
                                                  float* __restrict__ deg) {
  int wave = (blockIdx.x * 256 + threadIdx.x) >> 6;
  int lane = threadIdx.x & 63;
  if (wave >= E) return;
  int s = src_idx[wave];
  int d = dst_idx[wave];
  atomicAdd(&ssum[(size_t)d * 64 + lane], tab[(size_t)s * 64 + lane]);
  if (lane == 0) atomicAdd(&deg[d], 1.0f);
}

__global__ __launch_bounds__(256) void agg_rates_kernel(const float* __restrict__ u2e,
                                                        const float* __restrict__ v2e,
                                                        const int* __restrict__ rs,
                                                        const int* __restrict__ rd,
                                                        float* __restrict__ ssum_ru,
                                                        float* __restrict__ deg_ru,
                                                        float* __restrict__ ssum_v,
                                                        float* __restrict__ deg_v) {
  int wave = (blockIdx.x * 256 + threadIdx.x) >> 6;
  int lane = threadIdx.x & 63;
  if (wave >= ER) return;
  int s = rs[wave];   // user
  int d = rd[wave];   // item
  atomicAdd(&ssum_ru[(size_t)s * 64 + lane], v2e[(size_t)d * 64 + lane]);
  atomicAdd(&ssum_v[(size_t)d * 64 + lane], u2e[(size_t)s * 64 + lane]);
  if (lane == 0) { atomicAdd(&deg_ru[s], 1.0f); atomicAdd(&deg_v[d], 1.0f); }
}

__global__ __launch_bounds__(256) void hu_kernel(const float* __restrict__ u2e,
                                                 const float* __restrict__ wcomb,
                                                 const float* __restrict__ W_neigh,
                                                 const float* __restrict__ ssum_soc,
                                                 const float* __restrict__ deg_soc,
                                                 const float* __restrict__ ssum_ru,
                                                 const float* __restrict__ deg_ru,
                                                 float* __restrict__ h_u) {
  __shared__ float Wc[4096], W0[4096], W2[4096], bc[64];
  for (int i = threadIdx.x; i < 4096; i += 256) {
    Wc[i] = wcomb[i];
    W0[i] = W_neigh[i];
    W2[i] = W_neigh[8192 + i];
  }
  if (threadIdx.x < 64) bc[threadIdx.x] = wcomb[4096 + threadIdx.x];
  __syncthreads();
  int row = blockIdx.x * 256 + threadIdx.x;
  if (row >= NU) return;
  float4 acc[16];
#pragma unroll
  for (int j = 0; j < 16; ++j) acc[j] = ((const float4*)bc)[j];
  const float4* xr = (const float4*)&u2e[(size_t)row * 64];
  const float4* n0 = (const float4*)&ssum_soc[(size_t)row * 64];
  const float4* n2 = (const float4*)&ssum_ru[(size_t)row * 64];
  float inv0 = 1.0f / fmaxf(deg_soc[row], 1.0f);
  float inv2 = 1.0f / fmaxf(deg_ru[row], 1.0f);
#pragma unroll 1
  for (int k4 = 0; k4 < 16; ++k4) {
    float4 a = xr[k4], b0 = n0[k4], b2 = n2[k4];
#pragma unroll
    for (int kk = 0; kk < 4; ++kk) {
      int k = k4 * 4 + kk;
      fma_row((&a.x)[kk], &Wc[k * 64], acc);
      fma_row((&b0.x)[kk] * inv0, &W0[k * 64], acc);
      fma_row((&b2.x)[kk] * inv2, &W2[k * 64], acc);
    }
  }
  float4* o = (float4*)&h_u[(size_t)row * 64];
#pragma unroll
  for (int j = 0; j < 16; ++j) o[j] = acc[j];
}

__global__ __launch_bounds__(256) void hv_kernel(const float* __restrict__ v2e,
                                                 const float* __restrict__ W_self,
                                                 const float* __restrict__ b_self,
                                                 const float* __restrict__ W_neigh,
                                                 const float* __restrict__ ssum_v,
                                                 const float* __restrict__ deg_v,
                                                 float* __restrict__ h_v) {
  __shared__ float Ws[4096], Wn[4096], bl[64];
  for (int i = threadIdx.x; i < 4096; i += 256) {
    Ws[i] = W_self[4096 + i];
    Wn[i] = W_neigh[4096 + i];
  }
  if (threadIdx.x < 64) bl[threadIdx.x] = b_self[64 + threadIdx.x];
  __syncthreads();
  int row = blockIdx.x * 256 + threadIdx.x;
  if (row >= NV) return;
  float4 acc[16];
#pragma unroll
  for (int j = 0; j < 16; ++j) acc[j] = ((const float4*)bl)[j];
  const float4* xr = (const float4*)&v2e[(size_t)row * 64];
  const float4* nv = (const float4*)&ssum_v[(size_t)row * 64];
  float inv = 1.0f / fmaxf(deg_v[row], 1.0f);
#pragma unroll 1
  for (int k4 = 0; k4 < 16; ++k4) {
    float4 a = xr[k4], b0 = nv[k4];
#pragma unroll
    for (int kk = 0; kk < 4; ++kk) {
      int k = k4 * 4 + kk;
      fma_row((&a.x)[kk], &Ws[k * 64], acc);
      fma_row((&b0.x)[kk] * inv, &Wn[k * 64], acc);
    }
  }
  float4* o = (float4*)&h_v[(size_t)row * 64];
#pragma unroll
  for (int j = 0; j < 16; ++j) o[j] = acc[j];
}

__global__ __launch_bounds__(256) void lin_stats_kernel(const float* __restrict__ in,
                                                        const float* __restrict__ W,
                                                        const float* __restrict__ b, int N,
                                                        float* __restrict__ out,
                                                        float* __restrict__ ssum,
                                                        float* __restrict__ ssq) {
  __shared__ float Wl[4096], bl[64];
  for (int i = threadIdx.x; i < 4096; i += 256) Wl[i] = W[i];
  if (threadIdx.x < 64) bl[threadIdx.x] = b[threadIdx.x];
  __syncthreads();
  int row = blockIdx.x * 256 + threadIdx.x;
  bool valid = row < N;
  float4 acc[16];
#pragma unroll
  for (int j = 0; j < 16; ++j) acc[j] = ((const float4*)bl)[j];
  if (valid) {
    const float4* xr = (const float4*)&in[(size_t)row * 64];
#pragma unroll 1
    for (int k4 = 0; k4 < 16; ++k4) {
      float4 a = xr[k4];
#pragma unroll
      for (int kk = 0; kk < 4; ++kk) fma_row((&a.x)[kk], &Wl[(k4 * 4 + kk) * 64], acc);
    }
    float4* o = (float4*)&out[(size_t)row * 64];
#pragma unroll
    for (int j = 0; j < 16; ++j) o[j] = acc[j];
  }
  col_stats<16>(acc, valid, ssum, ssq);
}

__global__ void bn_final_kernel(const float* __restrict__ ssum, const float* __restrict__ ssq,
                                const float* __restrict__ gamma, const float* __restrict__ beta,
                                float n, int C, float* __restrict__ bnp) {
  int j = threadIdx.x;
  if (j >= C) return;
  float m = ssum[j] / n;
  float var = ssq[j] / n - m * m;
  float s = gamma[j] * rsqrtf(var + EPS_BN);
  bnp[j] = s;
  bnp[C + j] = beta[j] - m * s;
}

__global__ __launch_bounds__(256) void bnrelu_lin_kernel(const float* __restrict__ tin,
                                                         const float* __restrict__ bnp,
                                                         const float* __restrict__ W,
                                                         const float* __restrict__ b, int N,
                                                         float* __restrict__ xout) {
  __shared__ float Wl[4096], bl[64], sc[64], sh[64];
  for (int i = threadIdx.x; i < 4096; i += 256) Wl[i] = W[i];
  if (threadIdx.x < 64) {
    bl[threadIdx.x] = b[threadIdx.x];
    sc[threadIdx.x] = bnp[threadIdx.x];
    sh[threadIdx.x] = bnp[64 + threadIdx.x];
  }
  __syncthreads();
  int row = blockIdx.x * 256 + threadIdx.x;
  if (row >= N) return;
  float4 acc[16];
#pragma unroll
  for (int j = 0; j < 16; ++j) acc[j] = ((const float4*)bl)[j];
  const float4* xr = (const float4*)&tin[(size_t)row * 64];
#pragma unroll 1
  for (int k4 = 0; k4 < 16; ++k4) {
    float4 a = xr[k4];
#pragma unroll
    for (int kk = 0; kk < 4; ++kk) {
      int k = k4 * 4 + kk;
      float z = fmaxf(fmaf((&a.x)[kk], sc[k], sh[k]), 0.0f);
      fma_row(z, &Wl[k * 64], acc);
    }
  }
  float4* o = (float4*)&xout[(size_t)row * 64];
#pragma unroll
  for (int j = 0; j < 16; ++j) o[j] = acc[j];
}

// ---- e1: wave-per-edge, 64-edge tiles, LDS transpose, write y1T column-major.
// lane = output column j. W column j in 64 VGPRs; p broadcast via readlane.
__global__ __launch_bounds__(256) void e1_kernel(const float* __restrict__ xu,
                                                 const float* __restrict__ xv,
                                                 const int* __restrict__ rs,
                                                 const int* __restrict__ rd,
                                                 const float* __restrict__ W,
                                                 const float* __restrict__ b,
                                                 unsigned short* __restrict__ y1T,
                                                 float* __restrict__ ssum,
                                                 float* __restrict__ ssq) {
  __shared__ float tile[64][65];
  __shared__ float s1[64], s2[64];
  int lane = threadIdx.x & 63;
  int wave = threadIdx.x >> 6;   // 0..3
  if (threadIdx.x < 64) { s1[threadIdx.x] = 0.0f; s2[threadIdx.x] = 0.0f; }
  float wreg[64];
#pragma unroll
  for (int k = 0; k < 64; ++k) wreg[k] = W[k * 64 + lane];
  float bl = b[lane];
  float ssl = 0.0f, sql = 0.0f;
  __syncthreads();
  const int ntiles = ER / 64;    // 15625 exactly
  for (int t = blockIdx.x; t < ntiles; t += gridDim.x) {
    int e0 = t * 64;
#pragma unroll 1
    for (int i = 0; i < 16; ++i) {
      int e = e0 + wave * 16 + i;
      int s = rs[e], d = rd[e];
      float p = xu[(size_t)s * 64 + lane] * xv[(size_t)d * 64 + lane];
      float a0 = bl, a1 = 0.0f;
#pragma unroll
      for (int k = 0; k < 32; ++k) {
        float pk0 = __uint_as_float(__builtin_amdgcn_readlane(__float_as_uint(p), k));
        float pk1 = __uint_as_float(__builtin_amdgcn_readlane(__float_as_uint(p), k + 32));
        a0 = fmaf(pk0, wreg[k], a0);
        a1 = fmaf(pk1, wreg[k + 32], a1);
      }
      float acc = a0 + a1;
      tile[wave * 16 + i][lane] = acc;
      ssl += acc;
      sql = fmaf(acc, acc, sql);
    }
    __syncthreads();
    // transpose write: wave w writes columns w*16..w*16+15
#pragma unroll 1
    for (int i = 0; i < 16; ++i) {
      int j = wave * 16 + i;
      y1T[(size_t)j * ER + e0 + lane] = f2bf(tile[lane][j]);
    }
    __syncthreads();
  }
  atomicAdd(&s1[lane], ssl);
  atomicAdd(&s2[lane], sql);
  __syncthreads();
  if (threadIdx.x < 64) {
    atomicAdd(&ssum[threadIdx.x], s1[threadIdx.x]);
    atomicAdd(&ssq[threadIdx.x], s2[threadIdx.x]);
  }
}

// ---- e2: thread-per-edge on column-major y1T. Pure register FMAs, no shuffles
// in the hot loop. Writes y2T column-major.
__global__ __launch_bounds__(256) void e2_kernel(const unsigned short* __restrict__ y1T,
                                                 const float* __restrict__ bnp3,
                                                 const float* __restrict__ W,   // [64,16]
                                                 const float* __restrict__ b,   // [16]
                                                 unsigned short* __restrict__ y2T,
                                                 float* __restrict__ ssum,
                                                 float* __restrict__ ssq) {
  __shared__ float Wl[1024], bl[16], sc[64], sh[64], s1[16], s2[16];
  for (int i = threadIdx.x; i < 1024; i += 256) Wl[i] = W[i];
  if (threadIdx.x < 16) {
    bl[threadIdx.x] = b[threadIdx.x];
    s1[threadIdx.x] = 0.0f;
    s2[threadIdx.x] = 0.0f;
  }
  if (threadIdx.x < 64) { sc[threadIdx.x] = bnp3[threadIdx.x]; sh[threadIdx.x] = bnp3[64 + threadIdx.x]; }
  __syncthreads();
  float4 sa[4], sq[4];
#pragma unroll
  for (int j4 = 0; j4 < 4; ++j4) {
    sa[j4] = make_float4(0.f, 0.f, 0.f, 0.f);
    sq[j4] = make_float4(0.f, 0.f, 0.f, 0.f);
  }
  int stride = gridDim.x * 256;
  for (int e = blockIdx.x * 256 + threadIdx.x; e < ER; e += stride) {
    float4 acc[4];
#pragma unroll
    for (int j4 = 0; j4 < 4; ++j4) acc[j4] = ((const float4*)bl)[j4];
#pragma unroll 4
    for (int k = 0; k < 64; ++k) {
      float z = fmaxf(fmaf(bf2f(y1T[(size_t)k * ER + e]), sc[k], sh[k]), 0.0f);
      const float4* wr = (const float4*)&Wl[k * 16];
#pragma unroll
      for (int j4 = 0; j4 < 4; ++j4) {
        float4 w = wr[j4];
        acc[j4].x = fmaf(z, w.x, acc[j4].x);
        acc[j4].y = fmaf(z, w.y, acc[j4].y);
        acc[j4].z = fmaf(z, w.z, acc[j4].z);
        acc[j4].w = fmaf(z, w.w, acc[j4].w);
      }
    }
#pragma unroll
    for (int j4 = 0; j4 < 4; ++j4) {
#pragma unroll
      for (int c = 0; c < 4; ++c) {
        float v = (&acc[j4].x)[c];
        y2T[(size_t)(j4 * 4 + c) * ER + e] = f2bf(v);
        (&sa[j4].x)[c] += v;
        (&sq[j4].x)[c] = fmaf(v, v, (&sq[j4].x)[c]);
      }
    }
  }
  // wave reduce -> LDS -> global
#pragma unroll
  for (int j4 = 0; j4 < 4; ++j4) {
#pragma unroll
    for (int c = 0; c < 4; ++c) {
      float s = (&sa[j4].x)[c], q = (&sq[j4].x)[c];
#pragma unroll
      for (int off = 32; off >= 1; off >>= 1) {
        s += __shfl_down(s, off, 64);
        q += __shfl_down(q, off, 64);
      }
      if ((threadIdx.x & 63) == 0) {
        atomicAdd(&s1[j4 * 4 + c], s);
        atomicAdd(&s2[j4 * 4 + c], q);
      }
    }
  }
  __syncthreads();
  if (threadIdx.x < 16) {
    atomicAdd(&ssum[threadIdx.x], s1[threadIdx.x]);
    atomicAdd(&ssq[threadIdx.x], s2[threadIdx.x]);
  }
}

// ---- e3: thread-per-edge on column-major y2T (coalesced).
__global__ __launch_bounds__(256) void e3_kernel(const unsigned short* __restrict__ y2T,
                                                 const float* __restrict__ bnp4,
                                                 const float* __restrict__ w3,
                                                 const float* __restrict__ b3,
                                                 float* __restrict__ out) {
  __shared__ float sc[16], sh[16], wl[16];
  if (threadIdx.x < 16) {
    sc[threadIdx.x] = bnp4[threadIdx.x];
    sh[threadIdx.x] = bnp4[16 + threadIdx.x];
    wl[threadIdx.x] = w3[threadIdx.x];
  }
  __syncthreads();
  int e = blockIdx.x * 256 + threadIdx.x;
  if (e >= ER) return;
  float acc = b3[0];
#pragma unroll
  for (int j = 0; j < 16; ++j) {
    float v = bf2f(y2T[(size_t)j * ER + e]);
    float z = fmaxf(fmaf(v, sc[j], sh[j]), 0.0f);
    acc = fmaf(z, wl[j], acc);
  }
  out[e] = acc;
}

// ---------------- host ----------------
extern "C" void kernel_launch(void* const* d_in, const int* in_sizes, int n_in,
                              void* d_out, int out_size, void* d_ws, size_t ws_size,
                              hipStream_t stream) {
  const float* u2e = (const float*)d_in[0];
  const float* v2e = (const float*)d_in[1];
  const float* W_self = (const float*)d_in[2];
  const float* b_self = (const float*)d_in[3];
  const float* W_neigh = (const float*)d_in[4];
  const float* Wur1 = (const float*)d_in[5];
  const float* bur1 = (const float*)d_in[6];
  const float* Wur2 = (const float*)d_in[7];
  const float* bur2 = (const float*)d_in[8];
  const float* Wvr1 = (const float*)d_in[9];
  const float* bvr1 = (const float*)d_in[10];
  const float* Wvr2 = (const float*)d_in[11];
  const float* bvr2 = (const float*)d_in[12];
  const float* Wuv1 = (const float*)d_in[13];
  const float* buv1 = (const float*)d_in[14];
  const float* Wuv2 = (const float*)d_in[15];
  const float* buv2 = (const float*)d_in[16];
  const float* Wuv3 = (const float*)d_in[17];
  const float* buv3 = (const float*)d_in[18];
  const float* bn_gamma = (const float*)d_in[19];
  const float* bn_beta = (const float*)d_in[20];
  const float* bn4_gamma = (const float*)d_in[21];
  const float* bn4_beta = (const float*)d_in[22];
  const int* social_src = (const int*)d_in[23];
  const int* social_dst = (const int*)d_in[24];
  const int* rates_src = (const int*)d_in[25];
  const int* rates_dst = (const int*)d_in[26];
  float* out = (float*)d_out;
  float* ws = (float*)d_ws;

  float* A = ws + OFF_A;
  float* degS = ws + OFF_DEG_SOC;
  float* degR = ws + OFF_DEG_RU;
  float* degV = ws + OFF_DEG_V;
  float* Cb = ws + OFF_C;
  float* Db = ws + OFF_D;
  float* Eb = ws + OFF_E;
  float* Fb = ws + OFF_F;
  float* wcomb = ws + OFF_WCOMB;
  float* stats = ws + OFF_STATS;
  float* bnp = ws + OFF_BNP;
  unsigned short* y1T = (unsigned short*)((char*)d_ws + OFF_Y1_BYTES);
  unsigned short* y2T = (unsigned short*)((char*)d_ws + OFF_Y2_BYTES);

  hipMemsetAsync(ws, 0, (size_t)9750000 * sizeof(float), stream);
  hipMemsetAsync(stats, 0, 464 * sizeof(float), stream);

  wcomb_kernel<<<16, 256, 0, stream>>>(W_self, b_self, wcomb);

  agg_kernel<<<ES / 4, 256, 0, stream>>>(u2e, social_src, social_dst, ES, A, degS);
  agg_rates_kernel<<<ER / 4, 256, 0, stream>>>(u2e, v2e, rates_src, rates_dst, Cb, degR, Db, degV);

  hu_kernel<<<(NU + 255) / 256, 256, 0, stream>>>(u2e, wcomb, W_neigh, A, degS, Cb, degR, Eb);
  hv_kernel<<<(NV + 255) / 256, 256, 0, stream>>>(v2e, W_self, b_self, W_neigh, Db, degV, Fb);

  lin_stats_kernel<<<(NU + 255) / 256, 256, 0, stream>>>(Eb, Wur1, bur1, NU, A, stats + 0, stats + 64);
  lin_stats_kernel<<<(NV + 255) / 256, 256, 0, stream>>>(Fb, Wvr1, bvr1, NV, Cb, stats + 128, stats + 192);

  bn_final_kernel<<<1, 64, 0, stream>>>(stats + 0, stats + 64, bn_gamma, bn_beta, (float)NU, 64, bnp);
  bn_final_kernel<<<1, 64, 0, stream>>>(stats + 128, stats + 192, bn_gamma + 64, bn_beta + 64, (float)NV, 64, bnp + 128);

  bnrelu_lin_kernel<<<(NU + 255) / 256, 256, 0, stream>>>(A, bnp, Wur2, bur2, NU, Db);
  bnrelu_lin_kernel<<<(NV + 255) / 256, 256, 0, stream>>>(Cb, bnp + 128, Wvr2, bvr2, NV, Eb);

  e1_kernel<<<2048, 256, 0, stream>>>(Db, Eb, rates_src, rates_dst, Wuv1, buv1, y1T,
                                      stats + 256, stats + 320);
  bn_final_kernel<<<1, 64, 0, stream>>>(stats + 256, stats + 320, bn_gamma + 128, bn_beta + 128,
                                        (float)ER, 64, bnp + 256);
  e2_kernel<<<2048, 256, 0, stream>>>(y1T, bnp + 256, Wuv2, buv2, y2T,
                                      stats + 384, stats + 400);
  bn_final_kernel<<<1, 16, 0, stream>>>(stats + 384, stats + 400, bn4_gamma, bn4_beta,
                                        (float)ER, 16, bnp + 384);
  e3_kernel<<<(ER + 255) / 256, 256, 0, stream>>>(y2T, bnp + 384, Wuv3, buv3, out);
}

// Round 5
// 2094.736 us; speedup vs baseline: 5.4095x; 1.0489x over previous
//
#include <hip/hip_runtime.h>

#define NU 50000
#define NV 50000
#define ES 800000
#define ER 1000000
#define EPS_BN 1e-5f

// ---------------- workspace layout ----------------
// floats:
static const size_t OFF_A       = 0;         // mean_soc -> t_u
static const size_t OFF_C       = 3350000;   // mean_ru -> t_v
static const size_t OFF_D       = 6550000;   // mean_v  -> x_u
static const size_t OFF_E       = 9750000;   // h_u     -> x_v
static const size_t OFF_F       = 12950000;  // h_v
static const size_t OFF_WCOMB   = 16150000;
static const size_t OFF_STATS   = 16154160;
static const size_t OFF_BNP     = 16154624;
// bytes:
static const size_t OFF_Y1_BYTES = 64640000;   // y1T: [64][ER] bf16, 128MB (CSR scratch lives here pre-e1)
static const size_t OFF_Y2_BYTES = 192640000;  // y2T: [16][ER] bf16, 32MB
// CSR scratch inside y1 region (byte offsets relative to OFF_Y1_BYTES).
// All consumed before e1_kernel overwrites the region with y1T.
static const size_t CSR_IDX_S  = 0;          // ES ints
static const size_t CSR_IDX_RU = 3200000;    // ER ints
static const size_t CSR_IDX_V  = 7200000;    // ER ints
static const size_t CSR_CNT_S  = 11200000;   // NU ints
static const size_t CSR_CNT_RU = 11400000;   // NU ints
static const size_t CSR_CNT_V  = 11600000;   // NV ints
static const size_t CSR_CUR_S  = 11800000;   // NU ints
static const size_t CSR_CUR_RU = 12000000;   // NU ints
static const size_t CSR_CUR_V  = 12200000;   // NV ints
static const size_t CSR_OFF_S  = 12400000;   // NU+1 ints
static const size_t CSR_OFF_RU = 12600016;   // NU+1 ints
static const size_t CSR_OFF_V  = 12800032;   // NV+1 ints (ends ~13.0MB << 128MB)

// ---------------- helpers ----------------
__device__ __forceinline__ unsigned short f2bf(float f) {
  unsigned u = __float_as_uint(f);
  unsigned r = u + 0x7FFF + ((u >> 16) & 1);   // RNE (finite values)
  return (unsigned short)(r >> 16);
}
__device__ __forceinline__ float bf2f(unsigned short h) {
  return __uint_as_float(((unsigned)h) << 16);
}

__device__ __forceinline__ void fma_row(float xk, const float* __restrict__ wrow, float4* acc) {
  const float4* w = (const float4*)wrow;
#pragma unroll
  for (int j = 0; j < 16; ++j) {
    float4 wv = w[j];
    acc[j].x = fmaf(xk, wv.x, acc[j].x);
    acc[j].y = fmaf(xk, wv.y, acc[j].y);
    acc[j].z = fmaf(xk, wv.z, acc[j].z);
    acc[j].w = fmaf(xk, wv.w, acc[j].w);
  }
}

template <int NJ>
__device__ __forceinline__ void col_stats(const float4* acc, bool valid,
                                          float* __restrict__ ssum, float* __restrict__ ssq) {
#pragma unroll
  for (int j = 0; j < NJ; ++j) {
#pragma unroll
    for (int c = 0; c < 4; ++c) {
      float v = valid ? (&acc[j].x)[c] : 0.0f;
      float s = v, q = v * v;
#pragma unroll
      for (int off = 32; off >= 1; off >>= 1) {
        s += __shfl_down(s, off, 64);
        q += __shfl_down(q, off, 64);
      }
      if ((threadIdx.x & 63) == 0) {
        atomicAdd(&ssum[j * 4 + c], s);
        atomicAdd(&ssq[j * 4 + c], q);
      }
    }
  }
}

// ---------------- kernels ----------------
__global__ __launch_bounds__(256) void wcomb_kernel(const float* __restrict__ W_self,
                                                    const float* __restrict__ b_self,
                                                    float* __restrict__ wcomb) {
  int i = blockIdx.x * 256 + threadIdx.x;
  if (i < 4096) wcomb[i] = W_self[i] + W_self[8192 + i];
  if (i < 64) wcomb[4096 + i] = b_self[i] + b_self[128 + i];
}

// histogram all three destination sets
__global__ __launch_bounds__(256) void hist_kernel(const int* __restrict__ sd,
                                                   const int* __restrict__ rs,
                                                   const int* __restrict__ rd,
                                                   int* __restrict__ cnt_s,
                                                   int* __restrict__ cnt_ru,
                                                   int* __restrict__ cnt_v) {
  int stride = gridDim.x * 256;
  for (int e = blockIdx.x * 256 + threadIdx.x; e < ER; e += stride) {
    if (e < ES) atomicAdd(&cnt_s[sd[e]], 1);
    atomicAdd(&cnt_ru[rs[e]], 1);
    atomicAdd(&cnt_v[rd[e]], 1);
  }
}

// 3 blocks, one exclusive scan each; writes off[0..n] and cur[0..n-1]=off
__global__ __launch_bounds__(1024) void scan3_kernel(const int* __restrict__ c0, int n0, int* o0, int* u0,
                                                     const int* __restrict__ c1, int n1, int* o1, int* u1,
                                                     const int* __restrict__ c2, int n2, int* o2, int* u2) {
  const int* c; int n; int* o; int* u;
  if (blockIdx.x == 0) { c = c0; n = n0; o = o0; u = u0; }
  else if (blockIdx.x == 1) { c = c1; n = n1; o = o1; u = u1; }
  else { c = c2; n = n2; o = o2; u = u2; }
  __shared__ int buf[1024];
  __shared__ int carry_s;
  if (threadIdx.x == 0) carry_s = 0;
  __syncthreads();
  for (int base = 0; base < n; base += 1024) {
    int i = base + threadIdx.x;
    int v = (i < n) ? c[i] : 0;
    buf[threadIdx.x] = v;
    __syncthreads();
#pragma unroll
    for (int ofs = 1; ofs < 1024; ofs <<= 1) {
      int t = 0;
      if ((int)threadIdx.x >= ofs) t = buf[threadIdx.x - ofs];
      __syncthreads();
      buf[threadIdx.x] += t;
      __syncthreads();
    }
    int carry = carry_s;
    int excl = carry + buf[threadIdx.x] - v;
    if (i < n) { o[i] = excl; u[i] = excl; }
    __syncthreads();
    if (threadIdx.x == 0) carry_s += buf[1023];
    __syncthreads();
  }
  if (threadIdx.x == 0) o[n] = carry_s;
}

// scatter edge endpoints into CSR slots
__global__ __launch_bounds__(256) void scatter_kernel(const int* __restrict__ ss,
                                                      const int* __restrict__ sd,
                                                      const int* __restrict__ rs,
                                                      const int* __restrict__ rd,
                                                      int* __restrict__ cur_s,
                                                      int* __restrict__ cur_ru,
                                                      int* __restrict__ cur_v,
                                                      int* __restrict__ idx_s,
                                                      int* __restrict__ idx_ru,
                                                      int* __restrict__ idx_v) {
  int stride = gridDim.x * 256;
  for (int e = blockIdx.x * 256 + threadIdx.x; e < ER; e += stride) {
    if (e < ES) {
      int p = atomicAdd(&cur_s[sd[e]], 1);
      idx_s[p] = ss[e];
    }
    int s = rs[e], d = rd[e];
    int p = atomicAdd(&cur_ru[s], 1);
    idx_ru[p] = d;
    int q = atomicAdd(&cur_v[d], 1);
    idx_v[q] = s;
  }
}

// wave-per-node gather mean
__global__ __launch_bounds__(256) void gmean_kernel(const float* __restrict__ tab,
                                                    const int* __restrict__ off,
                                                    const int* __restrict__ idx, int N,
                                                    float* __restrict__ mean) {
  int wid = (blockIdx.x * 256 + threadIdx.x) >> 6;
  int lane = threadIdx.x & 63;
  if (wid >= N) return;
  int b = off[wid], e = off[wid + 1];
  float acc0 = 0.0f, acc1 = 0.0f;
  int i = b;
  for (; i + 1 < e; i += 2) {
    int n0 = idx[i], n1 = idx[i + 1];
    acc0 += tab[(size_t)n0 * 64 + lane];
    acc1 += tab[(size_t)n1 * 64 + lane];
  }
  if (i < e) acc0 += tab[(size_t)idx[i] * 64 + lane];
  float acc = acc0 + acc1;
  float inv = (e > b) ? 1.0f / (float)(e - b) : 0.0f;
  mean[(size_t)wid * 64 + lane] = acc * inv;
}

// h_u = u2e@Wcomb + bcomb + mean_soc@Wn0 + mean_ru@Wn2
__global__ __launch_bounds__(256) void hu_kernel(const float* __restrict__ u2e,
                                                 const float* __restrict__ wcomb,
                                                 const float* __restrict__ W_neigh,
                                                 const float* __restrict__ mean_soc,
                                                 const float* __restrict__ mean_ru,
                                                 float* __restrict__ h_u) {
  __shared__ float Wc[4096], W0[4096], W2[4096], bc[64];
  for (int i = threadIdx.x; i < 4096; i += 256) {
    Wc[i] = wcomb[i];
    W0[i] = W_neigh[i];
    W2[i] = W_neigh[8192 + i];
  }
  if (threadIdx.x < 64) bc[threadIdx.x] = wcomb[4096 + threadIdx.x];
  __syncthreads();
  int row = blockIdx.x * 256 + threadIdx.x;
  if (row >= NU) return;
  float4 acc[16];
#pragma unroll
  for (int j = 0; j < 16; ++j) acc[j] = ((const float4*)bc)[j];
  const float4* xr = (const float4*)&u2e[(size_t)row * 64];
  const float4* n0 = (const float4*)&mean_soc[(size_t)row * 64];
  const float4* n2 = (const float4*)&mean_ru[(size_t)row * 64];
#pragma unroll 1
  for (int k4 = 0; k4 < 16; ++k4) {
    float4 a = xr[k4], b0 = n0[k4], b2 = n2[k4];
#pragma unroll
    for (int kk = 0; kk < 4; ++kk) {
      int k = k4 * 4 + kk;
      fma_row((&a.x)[kk], &Wc[k * 64], acc);
      fma_row((&b0.x)[kk], &W0[k * 64], acc);
      fma_row((&b2.x)[kk], &W2[k * 64], acc);
    }
  }
  float4* o = (float4*)&h_u[(size_t)row * 64];
#pragma unroll
  for (int j = 0; j < 16; ++j) o[j] = acc[j];
}

__global__ __launch_bounds__(256) void hv_kernel(const float* __restrict__ v2e,
                                                 const float* __restrict__ W_self,
                                                 const float* __restrict__ b_self,
                                                 const float* __restrict__ W_neigh,
                                                 const float* __restrict__ mean_v,
                                                 float* __restrict__ h_v) {
  __shared__ float Ws[4096], Wn[4096], bl[64];
  for (int i = threadIdx.x; i < 4096; i += 256) {
    Ws[i] = W_self[4096 + i];
    Wn[i] = W_neigh[4096 + i];
  }
  if (threadIdx.x < 64) bl[threadIdx.x] = b_self[64 + threadIdx.x];
  __syncthreads();
  int row = blockIdx.x * 256 + threadIdx.x;
  if (row >= NV) return;
  float4 acc[16];
#pragma unroll
  for (int j = 0; j < 16; ++j) acc[j] = ((const float4*)bl)[j];
  const float4* xr = (const float4*)&v2e[(size_t)row * 64];
  const float4* nv = (const float4*)&mean_v[(size_t)row * 64];
#pragma unroll 1
  for (int k4 = 0; k4 < 16; ++k4) {
    float4 a = xr[k4], b0 = nv[k4];
#pragma unroll
    for (int kk = 0; kk < 4; ++kk) {
      int k = k4 * 4 + kk;
      fma_row((&a.x)[kk], &Ws[k * 64], acc);
      fma_row((&b0.x)[kk], &Wn[k * 64], acc);
    }
  }
  float4* o = (float4*)&h_v[(size_t)row * 64];
#pragma unroll
  for (int j = 0; j < 16; ++j) o[j] = acc[j];
}

__global__ __launch_bounds__(256) void lin_stats_kernel(const float* __restrict__ in,
                                                        const float* __restrict__ W,
                                                        const float* __restrict__ b, int N,
                                                        float* __restrict__ out,
                                                        float* __restrict__ ssum,
                                                        float* __restrict__ ssq) {
  __shared__ float Wl[4096], bl[64];
  for (int i = threadIdx.x; i < 4096; i += 256) Wl[i] = W[i];
  if (threadIdx.x < 64) bl[threadIdx.x] = b[threadIdx.x];
  __syncthreads();
  int row = blockIdx.x * 256 + threadIdx.x;
  bool valid = row < N;
  float4 acc[16];
#pragma unroll
  for (int j = 0; j < 16; ++j) acc[j] = ((const float4*)bl)[j];
  if (valid) {
    const float4* xr = (const float4*)&in[(size_t)row * 64];
#pragma unroll 1
    for (int k4 = 0; k4 < 16; ++k4) {
      float4 a = xr[k4];
#pragma unroll
      for (int kk = 0; kk < 4; ++kk) fma_row((&a.x)[kk], &Wl[(k4 * 4 + kk) * 64], acc);
    }
    float4* o = (float4*)&out[(size_t)row * 64];
#pragma unroll
    for (int j = 0; j < 16; ++j) o[j] = acc[j];
  }
  col_stats<16>(acc, valid, ssum, ssq);
}

__global__ void bn_final_kernel(const float* __restrict__ ssum, const float* __restrict__ ssq,
                                const float* __restrict__ gamma, const float* __restrict__ beta,
                                float n, int C, float* __restrict__ bnp) {
  int j = threadIdx.x;
  if (j >= C) return;
  float m = ssum[j] / n;
  float var = ssq[j] / n - m * m;
  float s = gamma[j] * rsqrtf(var + EPS_BN);
  bnp[j] = s;
  bnp[C + j] = beta[j] - m * s;
}

__global__ __launch_bounds__(256) void bnrelu_lin_kernel(const float* __restrict__ tin,
                                                         const float* __restrict__ bnp,
                                                         const float* __restrict__ W,
                                                         const float* __restrict__ b, int N,
                                                         float* __restrict__ xout) {
  __shared__ float Wl[4096], bl[64], sc[64], sh[64];
  for (int i = threadIdx.x; i < 4096; i += 256) Wl[i] = W[i];
  if (threadIdx.x < 64) {
    bl[threadIdx.x] = b[threadIdx.x];
    sc[threadIdx.x] = bnp[threadIdx.x];
    sh[threadIdx.x] = bnp[64 + threadIdx.x];
  }
  __syncthreads();
  int row = blockIdx.x * 256 + threadIdx.x;
  if (row >= N) return;
  float4 acc[16];
#pragma unroll
  for (int j = 0; j < 16; ++j) acc[j] = ((const float4*)bl)[j];
  const float4* xr = (const float4*)&tin[(size_t)row * 64];
#pragma unroll 1
  for (int k4 = 0; k4 < 16; ++k4) {
    float4 a = xr[k4];
#pragma unroll
    for (int kk = 0; kk < 4; ++kk) {
      int k = k4 * 4 + kk;
      float z = fmaxf(fmaf((&a.x)[kk], sc[k], sh[k]), 0.0f);
      fma_row(z, &Wl[k * 64], acc);
    }
  }
  float4* o = (float4*)&xout[(size_t)row * 64];
#pragma unroll
  for (int j = 0; j < 16; ++j) o[j] = acc[j];
}

// ---- e1: wave-per-edge, 64-edge tiles, LDS transpose, write y1T column-major.
__global__ __launch_bounds__(256) void e1_kernel(const float* __restrict__ xu,
                                                 const float* __restrict__ xv,
                                                 const int* __restrict__ rs,
                                                 const int* __restrict__ rd,
                                                 const float* __restrict__ W,
                                                 const float* __restrict__ b,
                                                 unsigned short* __restrict__ y1T,
                                                 float* __restrict__ ssum,
                                                 float* __restrict__ ssq) {
  __shared__ float tile[64][65];
  __shared__ float s1[64], s2[64];
  int lane = threadIdx.x & 63;
  int wave = threadIdx.x >> 6;   // 0..3
  if (threadIdx.x < 64) { s1[threadIdx.x] = 0.0f; s2[threadIdx.x] = 0.0f; }
  float wreg[64];
#pragma unroll
  for (int k = 0; k < 64; ++k) wreg[k] = W[k * 64 + lane];
  float bl = b[lane];
  float ssl = 0.0f, sql = 0.0f;
  __syncthreads();
  const int ntiles = ER / 64;    // 15625 exactly
  for (int t = blockIdx.x; t < ntiles; t += gridDim.x) {
    int e0 = t * 64;
#pragma unroll 1
    for (int i = 0; i < 16; ++i) {
      int e = e0 + wave * 16 + i;
      int s = rs[e], d = rd[e];
      float p = xu[(size_t)s * 64 + lane] * xv[(size_t)d * 64 + lane];
      float a0 = bl, a1 = 0.0f;
#pragma unroll
      for (int k = 0; k < 32; ++k) {
        float pk0 = __uint_as_float(__builtin_amdgcn_readlane(__float_as_uint(p), k));
        float pk1 = __uint_as_float(__builtin_amdgcn_readlane(__float_as_uint(p), k + 32));
        a0 = fmaf(pk0, wreg[k], a0);
        a1 = fmaf(pk1, wreg[k + 32], a1);
      }
      float acc = a0 + a1;
      tile[wave * 16 + i][lane] = acc;
      ssl += acc;
      sql = fmaf(acc, acc, sql);
    }
    __syncthreads();
#pragma unroll 1
    for (int i = 0; i < 16; ++i) {
      int j = wave * 16 + i;
      y1T[(size_t)j * ER + e0 + lane] = f2bf(tile[lane][j]);
    }
    __syncthreads();
  }
  atomicAdd(&s1[lane], ssl);
  atomicAdd(&s2[lane], sql);
  __syncthreads();
  if (threadIdx.x < 64) {
    atomicAdd(&ssum[threadIdx.x], s1[threadIdx.x]);
    atomicAdd(&ssq[threadIdx.x], s2[threadIdx.x]);
  }
}

// ---- e2: thread-per-edge on column-major y1T.
__global__ __launch_bounds__(256) void e2_kernel(const unsigned short* __restrict__ y1T,
                                                 const float* __restrict__ bnp3,
                                                 const float* __restrict__ W,   // [64,16]
                                                 const float* __restrict__ b,   // [16]
                                                 unsigned short* __restrict__ y2T,
                                                 float* __restrict__ ssum,
                                                 float* __restrict__ ssq) {
  __shared__ float Wl[1024], bl[16], sc[64], sh[64], s1[16], s2[16];
  for (int i = threadIdx.x; i < 1024; i += 256) Wl[i] = W[i];
  if (threadIdx.x < 16) {
    bl[threadIdx.x] = b[threadIdx.x];
    s1[threadIdx.x] = 0.0f;
    s2[threadIdx.x] = 0.0f;
  }
  if (threadIdx.x < 64) { sc[threadIdx.x] = bnp3[threadIdx.x]; sh[threadIdx.x] = bnp3[64 + threadIdx.x]; }
  __syncthreads();
  float4 sa[4], sq[4];
#pragma unroll
  for (int j4 = 0; j4 < 4; ++j4) {
    sa[j4] = make_float4(0.f, 0.f, 0.f, 0.f);
    sq[j4] = make_float4(0.f, 0.f, 0.f, 0.f);
  }
  int stride = gridDim.x * 256;
  for (int e = blockIdx.x * 256 + threadIdx.x; e < ER; e += stride) {
    float4 acc[4];
#pragma unroll
    for (int j4 = 0; j4 < 4; ++j4) acc[j4] = ((const float4*)bl)[j4];
#pragma unroll 4
    for (int k = 0; k < 64; ++k) {
      float z = fmaxf(fmaf(bf2f(y1T[(size_t)k * ER + e]), sc[k], sh[k]), 0.0f);
      const float4* wr = (const float4*)&Wl[k * 16];
#pragma unroll
      for (int j4 = 0; j4 < 4; ++j4) {
        float4 w = wr[j4];
        acc[j4].x = fmaf(z, w.x, acc[j4].x);
        acc[j4].y = fmaf(z, w.y, acc[j4].y);
        acc[j4].z = fmaf(z, w.z, acc[j4].z);
        acc[j4].w = fmaf(z, w.w, acc[j4].w);
      }
    }
#pragma unroll
    for (int j4 = 0; j4 < 4; ++j4) {
#pragma unroll
      for (int c = 0; c < 4; ++c) {
        float v = (&acc[j4].x)[c];
        y2T[(size_t)(j4 * 4 + c) * ER + e] = f2bf(v);
        (&sa[j4].x)[c] += v;
        (&sq[j4].x)[c] = fmaf(v, v, (&sq[j4].x)[c]);
      }
    }
  }
#pragma unroll
  for (int j4 = 0; j4 < 4; ++j4) {
#pragma unroll
    for (int c = 0; c < 4; ++c) {
      float s = (&sa[j4].x)[c], q = (&sq[j4].x)[c];
#pragma unroll
      for (int off = 32; off >= 1; off >>= 1) {
        s += __shfl_down(s, off, 64);
        q += __shfl_down(q, off, 64);
      }
      if ((threadIdx.x & 63) == 0) {
        atomicAdd(&s1[j4 * 4 + c], s);
        atomicAdd(&s2[j4 * 4 + c], q);
      }
    }
  }
  __syncthreads();
  if (threadIdx.x < 16) {
    atomicAdd(&ssum[threadIdx.x], s1[threadIdx.x]);
    atomicAdd(&ssq[threadIdx.x], s2[threadIdx.x]);
  }
}

__global__ __launch_bounds__(256) void e3_kernel(const unsigned short* __restrict__ y2T,
                                                 const float* __restrict__ bnp4,
                                                 const float* __restrict__ w3,
                                                 const float* __restrict__ b3,
                                                 float* __restrict__ out) {
  __shared__ float sc[16], sh[16], wl[16];
  if (threadIdx.x < 16) {
    sc[threadIdx.x] = bnp4[threadIdx.x];
    sh[threadIdx.x] = bnp4[16 + threadIdx.x];
    wl[threadIdx.x] = w3[threadIdx.x];
  }
  __syncthreads();
  int e = blockIdx.x * 256 + threadIdx.x;
  if (e >= ER) return;
  float acc = b3[0];
#pragma unroll
  for (int j = 0; j < 16; ++j) {
    float v = bf2f(y2T[(size_t)j * ER + e]);
    float z = fmaxf(fmaf(v, sc[j], sh[j]), 0.0f);
    acc = fmaf(z, wl[j], acc);
  }
  out[e] = acc;
}

// ---------------- host ----------------
extern "C" void kernel_launch(void* const* d_in, const int* in_sizes, int n_in,
                              void* d_out, int out_size, void* d_ws, size_t ws_size,
                              hipStream_t stream) {
  const float* u2e = (const float*)d_in[0];
  const float* v2e = (const float*)d_in[1];
  const float* W_self = (const float*)d_in[2];
  const float* b_self = (const float*)d_in[3];
  const float* W_neigh = (const float*)d_in[4];
  const float* Wur1 = (const float*)d_in[5];
  const float* bur1 = (const float*)d_in[6];
  const float* Wur2 = (const float*)d_in[7];
  const float* bur2 = (const float*)d_in[8];
  const float* Wvr1 = (const float*)d_in[9];
  const float* bvr1 = (const float*)d_in[10];
  const float* Wvr2 = (const float*)d_in[11];
  const float* bvr2 = (const float*)d_in[12];
  const float* Wuv1 = (const float*)d_in[13];
  const float* buv1 = (const float*)d_in[14];
  const float* Wuv2 = (const float*)d_in[15];
  const float* buv2 = (const float*)d_in[16];
  const float* Wuv3 = (const float*)d_in[17];
  const float* buv3 = (const float*)d_in[18];
  const float* bn_gamma = (const float*)d_in[19];
  const float* bn_beta = (const float*)d_in[20];
  const float* bn4_gamma = (const float*)d_in[21];
  const float* bn4_beta = (const float*)d_in[22];
  const int* social_src = (const int*)d_in[23];
  const int* social_dst = (const int*)d_in[24];
  const int* rates_src = (const int*)d_in[25];
  const int* rates_dst = (const int*)d_in[26];
  float* out = (float*)d_out;
  float* ws = (float*)d_ws;

  float* A = ws + OFF_A;
  float* Cb = ws + OFF_C;
  float* Db = ws + OFF_D;
  float* Eb = ws + OFF_E;
  float* Fb = ws + OFF_F;
  float* wcomb = ws + OFF_WCOMB;
  float* stats = ws + OFF_STATS;
  float* bnp = ws + OFF_BNP;
  char* y1base = (char*)d_ws + OFF_Y1_BYTES;
  int* idx_s  = (int*)(y1base + CSR_IDX_S);
  int* idx_ru = (int*)(y1base + CSR_IDX_RU);
  int* idx_v  = (int*)(y1base + CSR_IDX_V);
  int* cnt_s  = (int*)(y1base + CSR_CNT_S);
  int* cnt_ru = (int*)(y1base + CSR_CNT_RU);
  int* cnt_v  = (int*)(y1base + CSR_CNT_V);
  int* cur_s  = (int*)(y1base + CSR_CUR_S);
  int* cur_ru = (int*)(y1base + CSR_CUR_RU);
  int* cur_v  = (int*)(y1base + CSR_CUR_V);
  int* off_s  = (int*)(y1base + CSR_OFF_S);
  int* off_ru = (int*)(y1base + CSR_OFF_RU);
  int* off_v  = (int*)(y1base + CSR_OFF_V);
  unsigned short* y1T = (unsigned short*)y1base;
  unsigned short* y2T = (unsigned short*)((char*)d_ws + OFF_Y2_BYTES);

  // zero: histogram counters (600KB, cnt_s..cnt_v contiguous) + stats
  hipMemsetAsync(cnt_s, 0, 3 * (size_t)NU * sizeof(int), stream);
  hipMemsetAsync(stats, 0, 464 * sizeof(float), stream);

  wcomb_kernel<<<16, 256, 0, stream>>>(W_self, b_self, wcomb);

  // CSR build
  hist_kernel<<<2048, 256, 0, stream>>>(social_dst, rates_src, rates_dst, cnt_s, cnt_ru, cnt_v);
  scan3_kernel<<<3, 1024, 0, stream>>>(cnt_s, NU, off_s, cur_s,
                                       cnt_ru, NU, off_ru, cur_ru,
                                       cnt_v, NV, off_v, cur_v);
  scatter_kernel<<<2048, 256, 0, stream>>>(social_src, social_dst, rates_src, rates_dst,
                                           cur_s, cur_ru, cur_v, idx_s, idx_ru, idx_v);
  // gather means
  gmean_kernel<<<(NU * 64 + 255) / 256, 256, 0, stream>>>(u2e, off_s, idx_s, NU, A);
  gmean_kernel<<<(NU * 64 + 255) / 256, 256, 0, stream>>>(v2e, off_ru, idx_ru, NU, Cb);
  gmean_kernel<<<(NV * 64 + 255) / 256, 256, 0, stream>>>(u2e, off_v, idx_v, NV, Db);

  hu_kernel<<<(NU + 255) / 256, 256, 0, stream>>>(u2e, wcomb, W_neigh, A, Cb, Eb);
  hv_kernel<<<(NV + 255) / 256, 256, 0, stream>>>(v2e, W_self, b_self, W_neigh, Db, Fb);

  lin_stats_kernel<<<(NU + 255) / 256, 256, 0, stream>>>(Eb, Wur1, bur1, NU, A, stats + 0, stats + 64);
  lin_stats_kernel<<<(NV + 255) / 256, 256, 0, stream>>>(Fb, Wvr1, bvr1, NV, Cb, stats + 128, stats + 192);

  bn_final_kernel<<<1, 64, 0, stream>>>(stats + 0, stats + 64, bn_gamma, bn_beta, (float)NU, 64, bnp);
  bn_final_kernel<<<1, 64, 0, stream>>>(stats + 128, stats + 192, bn_gamma + 64, bn_beta + 64, (float)NV, 64, bnp + 128);

  bnrelu_lin_kernel<<<(NU + 255) / 256, 256, 0, stream>>>(A, bnp, Wur2, bur2, NU, Db);
  bnrelu_lin_kernel<<<(NV + 255) / 256, 256, 0, stream>>>(Cb, bnp + 128, Wvr2, bvr2, NV, Eb);

  e1_kernel<<<2048, 256, 0, stream>>>(Db, Eb, rates_src, rates_dst, Wuv1, buv1, y1T,
                                      stats + 256, stats + 320);
  bn_final_kernel<<<1, 64, 0, stream>>>(stats + 256, stats + 320, bn_gamma + 128, bn_beta + 128,
                                        (float)ER, 64, bnp + 256);
  e2_kernel<<<2048, 256, 0, stream>>>(y1T, bnp + 256, Wuv2, buv2, y2T,
                                      stats + 384, stats + 400);
  bn_final_kernel<<<1, 16, 0, stream>>>(stats + 384, stats + 400, bn4_gamma, bn4_beta,
                                        (float)ER, 16, bnp + 384);
  e3_kernel<<<(ER + 255) / 256, 256, 0, stream>>>(y2T, bnp + 384, Wuv3, buv3, out);
}

// Round 6
// 1464.197 us; speedup vs baseline: 7.7391x; 1.4306x over previous
//
#include <hip/hip_runtime.h>

#define NU 50000
#define NV 50000
#define ES 800000
#define ER 1000000
#define EPS_BN 1e-5f

// ---------------- workspace layout ----------------
// floats:
static const size_t OFF_A       = 0;         // mean_soc -> t_u
static const size_t OFF_C       = 3350000;   // mean_ru -> t_v
static const size_t OFF_D       = 6550000;   // mean_v  -> x_u
static const size_t OFF_E       = 9750000;   // h_u     -> x_v
static const size_t OFF_F       = 12950000;  // h_v
static const size_t OFF_WCOMB   = 16150000;
static const size_t OFF_STATS   = 16154160;
static const size_t OFF_BNP     = 16154624;
// bytes:
static const size_t OFF_Y1_BYTES = 64640000;   // y1T: [64][ER] bf16, 128MB (CSR scratch pre-e1)
static const size_t OFF_Y2_BYTES = 192640000;  // y2T: [16][ER] bf16, 32MB
// CSR scratch inside y1 region (byte offsets rel. to OFF_Y1_BYTES), consumed before e1.
static const size_t CSR_IDX_S  = 0;
static const size_t CSR_IDX_RU = 3200000;
static const size_t CSR_IDX_V  = 7200000;
static const size_t CSR_CNT_S  = 11200000;
static const size_t CSR_CNT_RU = 11400000;
static const size_t CSR_CNT_V  = 11600000;
static const size_t CSR_CUR_S  = 11800000;
static const size_t CSR_CUR_RU = 12000000;
static const size_t CSR_CUR_V  = 12200000;
static const size_t CSR_OFF_S  = 12400000;
static const size_t CSR_OFF_RU = 12600016;
static const size_t CSR_OFF_V  = 12800032;

#define REP16(M) M(0) M(1) M(2) M(3) M(4) M(5) M(6) M(7) M(8) M(9) M(10) M(11) M(12) M(13) M(14) M(15)
#define REP4(M) M(0) M(1) M(2) M(3)

// ---------------- helpers ----------------
__device__ __forceinline__ unsigned short f2bf(float f) {
  unsigned u = __float_as_uint(f);
  unsigned r = u + 0x7FFF + ((u >> 16) & 1);   // RNE (finite values)
  return (unsigned short)(r >> 16);
}
__device__ __forceinline__ float bf2f(unsigned short h) {
  return __uint_as_float(((unsigned)h) << 16);
}

__device__ __forceinline__ void fma_row(float xk, const float* __restrict__ wrow, float4* acc) {
  const float4* w = (const float4*)wrow;
#pragma unroll
  for (int j = 0; j < 16; ++j) {
    float4 wv = w[j];
    acc[j].x = fmaf(xk, wv.x, acc[j].x);
    acc[j].y = fmaf(xk, wv.y, acc[j].y);
    acc[j].z = fmaf(xk, wv.z, acc[j].z);
    acc[j].w = fmaf(xk, wv.w, acc[j].w);
  }
}

// ---------------- kernels ----------------
__global__ __launch_bounds__(256) void wcomb_kernel(const float* __restrict__ W_self,
                                                    const float* __restrict__ b_self,
                                                    float* __restrict__ wcomb) {
  int i = blockIdx.x * 256 + threadIdx.x;
  if (i < 4096) wcomb[i] = W_self[i] + W_self[8192 + i];
  if (i < 64) wcomb[4096 + i] = b_self[i] + b_self[128 + i];
}

__global__ __launch_bounds__(256) void hist_kernel(const int* __restrict__ sd,
                                                   const int* __restrict__ rs,
                                                   const int* __restrict__ rd,
                                                   int* __restrict__ cnt_s,
                                                   int* __restrict__ cnt_ru,
                                                   int* __restrict__ cnt_v) {
  int stride = gridDim.x * 256;
  for (int e = blockIdx.x * 256 + threadIdx.x; e < ER; e += stride) {
    if (e < ES) atomicAdd(&cnt_s[sd[e]], 1);
    atomicAdd(&cnt_ru[rs[e]], 1);
    atomicAdd(&cnt_v[rd[e]], 1);
  }
}

__global__ __launch_bounds__(1024) void scan3_kernel(const int* __restrict__ c0, int n0, int* o0, int* u0,
                                                     const int* __restrict__ c1, int n1, int* o1, int* u1,
                                                     const int* __restrict__ c2, int n2, int* o2, int* u2) {
  const int* c; int n; int* o; int* u;
  if (blockIdx.x == 0) { c = c0; n = n0; o = o0; u = u0; }
  else if (blockIdx.x == 1) { c = c1; n = n1; o = o1; u = u1; }
  else { c = c2; n = n2; o = o2; u = u2; }
  __shared__ int buf[1024];
  __shared__ int carry_s;
  if (threadIdx.x == 0) carry_s = 0;
  __syncthreads();
  for (int base = 0; base < n; base += 1024) {
    int i = base + threadIdx.x;
    int v = (i < n) ? c[i] : 0;
    buf[threadIdx.x] = v;
    __syncthreads();
#pragma unroll
    for (int ofs = 1; ofs < 1024; ofs <<= 1) {
      int t = 0;
      if ((int)threadIdx.x >= ofs) t = buf[threadIdx.x - ofs];
      __syncthreads();
      buf[threadIdx.x] += t;
      __syncthreads();
    }
    int carry = carry_s;
    int excl = carry + buf[threadIdx.x] - v;
    if (i < n) { o[i] = excl; u[i] = excl; }
    __syncthreads();
    if (threadIdx.x == 0) carry_s += buf[1023];
    __syncthreads();
  }
  if (threadIdx.x == 0) o[n] = carry_s;
}

__global__ __launch_bounds__(256) void scatter_kernel(const int* __restrict__ ss,
                                                      const int* __restrict__ sd,
                                                      const int* __restrict__ rs,
                                                      const int* __restrict__ rd,
                                                      int* __restrict__ cur_s,
                                                      int* __restrict__ cur_ru,
                                                      int* __restrict__ cur_v,
                                                      int* __restrict__ idx_s,
                                                      int* __restrict__ idx_ru,
                                                      int* __restrict__ idx_v) {
  int stride = gridDim.x * 256;
  for (int e = blockIdx.x * 256 + threadIdx.x; e < ER; e += stride) {
    if (e < ES) {
      int p = atomicAdd(&cur_s[sd[e]], 1);
      idx_s[p] = ss[e];
    }
    int s = rs[e], d = rd[e];
    int p = atomicAdd(&cur_ru[s], 1);
    idx_ru[p] = d;
    int q = atomicAdd(&cur_v[d], 1);
    idx_v[q] = s;
  }
}

__global__ __launch_bounds__(256) void gmean_kernel(const float* __restrict__ tab,
                                                    const int* __restrict__ off,
                                                    const int* __restrict__ idx, int N,
                                                    float* __restrict__ mean) {
  int wid = (blockIdx.x * 256 + threadIdx.x) >> 6;
  int lane = threadIdx.x & 63;
  if (wid >= N) return;
  int b = off[wid], e = off[wid + 1];
  float acc0 = 0.0f, acc1 = 0.0f;
  int i = b;
  for (; i + 1 < e; i += 2) {
    int n0 = idx[i], n1 = idx[i + 1];
    acc0 += tab[(size_t)n0 * 64 + lane];
    acc1 += tab[(size_t)n1 * 64 + lane];
  }
  if (i < e) acc0 += tab[(size_t)idx[i] * 64 + lane];
  float acc = acc0 + acc1;
  float inv = (e > b) ? 1.0f / (float)(e - b) : 0.0f;
  mean[(size_t)wid * 64 + lane] = acc * inv;
}

__global__ __launch_bounds__(256) void hu_kernel(const float* __restrict__ u2e,
                                                 const float* __restrict__ wcomb,
                                                 const float* __restrict__ W_neigh,
                                                 const float* __restrict__ mean_soc,
                                                 const float* __restrict__ mean_ru,
                                                 float* __restrict__ h_u) {
  __shared__ float Wc[4096], W0[4096], W2[4096], bc[64];
  for (int i = threadIdx.x; i < 4096; i += 256) {
    Wc[i] = wcomb[i];
    W0[i] = W_neigh[i];
    W2[i] = W_neigh[8192 + i];
  }
  if (threadIdx.x < 64) bc[threadIdx.x] = wcomb[4096 + threadIdx.x];
  __syncthreads();
  int row = blockIdx.x * 256 + threadIdx.x;
  if (row >= NU) return;
  float4 acc[16];
#pragma unroll
  for (int j = 0; j < 16; ++j) acc[j] = ((const float4*)bc)[j];
  const float4* xr = (const float4*)&u2e[(size_t)row * 64];
  const float4* n0 = (const float4*)&mean_soc[(size_t)row * 64];
  const float4* n2 = (const float4*)&mean_ru[(size_t)row * 64];
#pragma unroll 1
  for (int k4 = 0; k4 < 16; ++k4) {
    float4 a = xr[k4], b0 = n0[k4], b2 = n2[k4];
#pragma unroll
    for (int kk = 0; kk < 4; ++kk) {
      int k = k4 * 4 + kk;
      fma_row((&a.x)[kk], &Wc[k * 64], acc);
      fma_row((&b0.x)[kk], &W0[k * 64], acc);
      fma_row((&b2.x)[kk], &W2[k * 64], acc);
    }
  }
  float4* o = (float4*)&h_u[(size_t)row * 64];
#pragma unroll
  for (int j = 0; j < 16; ++j) o[j] = acc[j];
}

__global__ __launch_bounds__(256) void hv_kernel(const float* __restrict__ v2e,
                                                 const float* __restrict__ W_self,
                                                 const float* __restrict__ b_self,
                                                 const float* __restrict__ W_neigh,
                                                 const float* __restrict__ mean_v,
                                                 float* __restrict__ h_v) {
  __shared__ float Ws[4096], Wn[4096], bl[64];
  for (int i = threadIdx.x; i < 4096; i += 256) {
    Ws[i] = W_self[4096 + i];
    Wn[i] = W_neigh[4096 + i];
  }
  if (threadIdx.x < 64) bl[threadIdx.x] = b_self[64 + threadIdx.x];
  __syncthreads();
  int row = blockIdx.x * 256 + threadIdx.x;
  if (row >= NV) return;
  float4 acc[16];
#pragma unroll
  for (int j = 0; j < 16; ++j) acc[j] = ((const float4*)bl)[j];
  const float4* xr = (const float4*)&v2e[(size_t)row * 64];
  const float4* nv = (const float4*)&mean_v[(size_t)row * 64];
#pragma unroll 1
  for (int k4 = 0; k4 < 16; ++k4) {
    float4 a = xr[k4], b0 = nv[k4];
#pragma unroll
    for (int kk = 0; kk < 4; ++kk) {
      int k = k4 * 4 + kk;
      fma_row((&a.x)[kk], &Ws[k * 64], acc);
      fma_row((&b0.x)[kk], &Wn[k * 64], acc);
    }
  }
  float4* o = (float4*)&h_v[(size_t)row * 64];
#pragma unroll
  for (int j = 0; j < 16; ++j) o[j] = acc[j];
}

// ---- lin_stats: thread-per-row, acc in NAMED float4 registers (no address-taking,
// no scratch spill), stats via inline scalar shuffle reduce.
#define CSTAT(VAL, IDX) { \
  float s_ = valid ? (VAL) : 0.0f; float q_ = s_ * s_; \
  s_ += __shfl_down(s_, 32, 64); q_ += __shfl_down(q_, 32, 64); \
  s_ += __shfl_down(s_, 16, 64); q_ += __shfl_down(q_, 16, 64); \
  s_ += __shfl_down(s_, 8, 64);  q_ += __shfl_down(q_, 8, 64); \
  s_ += __shfl_down(s_, 4, 64);  q_ += __shfl_down(q_, 4, 64); \
  s_ += __shfl_down(s_, 2, 64);  q_ += __shfl_down(q_, 2, 64); \
  s_ += __shfl_down(s_, 1, 64);  q_ += __shfl_down(q_, 1, 64); \
  if ((threadIdx.x & 63) == 0) { atomicAdd(&s1[IDX], s_); atomicAdd(&s2[IDX], q_); } }

__global__ __launch_bounds__(256) void lin_stats_kernel(const float* __restrict__ in,
                                                        const float* __restrict__ W,
                                                        const float* __restrict__ b, int N,
                                                        float* __restrict__ out,
                                                        float* __restrict__ ssum,
                                                        float* __restrict__ ssq) {
  __shared__ float Wl[4096], bl[64], s1[64], s2[64];
  for (int i = threadIdx.x; i < 4096; i += 256) Wl[i] = W[i];
  if (threadIdx.x < 64) {
    bl[threadIdx.x] = b[threadIdx.x];
    s1[threadIdx.x] = 0.0f;
    s2[threadIdx.x] = 0.0f;
  }
  __syncthreads();
  int row = blockIdx.x * 256 + threadIdx.x;
  bool valid = row < N;
  const float4* bl4 = (const float4*)bl;
#define LS_DECL(I) float4 A##I;
  REP16(LS_DECL)
#define LS_INIT(I) A##I = bl4[I];
  REP16(LS_INIT)
  if (valid) {
    const float4* xr = (const float4*)&in[(size_t)row * 64];
#define LS_FMA(I) { float4 w_ = W4_[I]; \
    A##I.x = fmaf(z_, w_.x, A##I.x); A##I.y = fmaf(z_, w_.y, A##I.y); \
    A##I.z = fmaf(z_, w_.z, A##I.z); A##I.w = fmaf(z_, w_.w, A##I.w); }
#define LS_DOFMA(ZV, K) { float z_ = (ZV); const float4* W4_ = (const float4*)&Wl[(K) * 64]; REP16(LS_FMA) }
#pragma unroll
    for (int k4 = 0; k4 < 16; ++k4) {
      float4 xa = xr[k4];
      LS_DOFMA(xa.x, k4 * 4 + 0)
      LS_DOFMA(xa.y, k4 * 4 + 1)
      LS_DOFMA(xa.z, k4 * 4 + 2)
      LS_DOFMA(xa.w, k4 * 4 + 3)
    }
    float4* o4 = (float4*)&out[(size_t)row * 64];
#define LS_ST(I) o4[I] = A##I;
    REP16(LS_ST)
  }
#define LS_CST(I) CSTAT(A##I.x, 4 * (I) + 0) CSTAT(A##I.y, 4 * (I) + 1) \
                  CSTAT(A##I.z, 4 * (I) + 2) CSTAT(A##I.w, 4 * (I) + 3)
  REP16(LS_CST)
  __syncthreads();
  if (threadIdx.x < 64) {
    atomicAdd(&ssum[threadIdx.x], s1[threadIdx.x]);
    atomicAdd(&ssq[threadIdx.x], s2[threadIdx.x]);
  }
}

__global__ __launch_bounds__(256) void bn_final_kernel(const float* __restrict__ ssum,
                                                       const float* __restrict__ ssq,
                                                       const float* __restrict__ gamma,
                                                       const float* __restrict__ beta,
                                                       float n, int C, float* __restrict__ bnp) {
  int j = threadIdx.x;
  if (j >= C) return;
  float m = ssum[j] / n;
  float var = ssq[j] / n - m * m;
  float s = gamma[j] * rsqrtf(var + EPS_BN);
  bnp[j] = s;
  bnp[C + j] = beta[j] - m * s;
}

__global__ __launch_bounds__(256) void bnrelu_lin_kernel(const float* __restrict__ tin,
                                                         const float* __restrict__ bnp,
                                                         const float* __restrict__ W,
                                                         const float* __restrict__ b, int N,
                                                         float* __restrict__ xout) {
  __shared__ float Wl[4096], bl[64], sc[64], sh[64];
  for (int i = threadIdx.x; i < 4096; i += 256) Wl[i] = W[i];
  if (threadIdx.x < 64) {
    bl[threadIdx.x] = b[threadIdx.x];
    sc[threadIdx.x] = bnp[threadIdx.x];
    sh[threadIdx.x] = bnp[64 + threadIdx.x];
  }
  __syncthreads();
  int row = blockIdx.x * 256 + threadIdx.x;
  if (row >= N) return;
  float4 acc[16];
#pragma unroll
  for (int j = 0; j < 16; ++j) acc[j] = ((const float4*)bl)[j];
  const float4* xr = (const float4*)&tin[(size_t)row * 64];
#pragma unroll 1
  for (int k4 = 0; k4 < 16; ++k4) {
    float4 a = xr[k4];
#pragma unroll
    for (int kk = 0; kk < 4; ++kk) {
      int k = k4 * 4 + kk;
      float z = fmaxf(fmaf((&a.x)[kk], sc[k], sh[k]), 0.0f);
      fma_row(z, &Wl[k * 64], acc);
    }
  }
  float4* o = (float4*)&xout[(size_t)row * 64];
#pragma unroll
  for (int j = 0; j < 16; ++j) o[j] = acc[j];
}

// ---- e1: wave-per-edge, W column in NAMED float4 regs, readlane broadcasts,
// LDS transpose, y1T column-major writes.
__global__ __launch_bounds__(256) void e1_kernel(const float* __restrict__ xu,
                                                 const float* __restrict__ xv,
                                                 const int* __restrict__ rs,
                                                 const int* __restrict__ rd,
                                                 const float* __restrict__ W,
                                                 const float* __restrict__ b,
                                                 unsigned short* __restrict__ y1T,
                                                 float* __restrict__ ssum,
                                                 float* __restrict__ ssq) {
  __shared__ float tile[64][65];
  __shared__ float s1[64], s2[64];
  int lane = threadIdx.x & 63;
  int wave = threadIdx.x >> 6;   // 0..3
  if (threadIdx.x < 64) { s1[threadIdx.x] = 0.0f; s2[threadIdx.x] = 0.0f; }
#define E1_DECLW(I) float4 WA##I;
  REP16(E1_DECLW)
#define E1_LDW(I) WA##I.x = W[(4 * (I) + 0) * 64 + lane]; \
                  WA##I.y = W[(4 * (I) + 1) * 64 + lane]; \
                  WA##I.z = W[(4 * (I) + 2) * 64 + lane]; \
                  WA##I.w = W[(4 * (I) + 3) * 64 + lane];
  REP16(E1_LDW)
  float bl = b[lane];
  float ssl = 0.0f, sql = 0.0f;
  __syncthreads();
  const int ntiles = ER / 64;    // 15625 exactly
  for (int t = blockIdx.x; t < ntiles; t += gridDim.x) {
    int e0 = t * 64;
#pragma unroll 1
    for (int i = 0; i < 16; ++i) {
      int e = e0 + wave * 16 + i;
      int s = rs[e], d = rd[e];
      float p = xu[(size_t)s * 64 + lane] * xv[(size_t)d * 64 + lane];
      unsigned pu = __float_as_uint(p);
      float a0_ = bl, a1_ = 0.0f;
#define E1_RL(K) __uint_as_float(__builtin_amdgcn_readlane(pu, (K)))
#define E1_FMA(I) a0_ = fmaf(E1_RL(4 * (I) + 0), WA##I.x, a0_); \
                  a1_ = fmaf(E1_RL(4 * (I) + 1), WA##I.y, a1_); \
                  a0_ = fmaf(E1_RL(4 * (I) + 2), WA##I.z, a0_); \
                  a1_ = fmaf(E1_RL(4 * (I) + 3), WA##I.w, a1_);
      REP16(E1_FMA)
      float acc = a0_ + a1_;
      tile[wave * 16 + i][lane] = acc;
      ssl += acc;
      sql = fmaf(acc, acc, sql);
    }
    __syncthreads();
#pragma unroll 1
    for (int i = 0; i < 16; ++i) {
      int j = wave * 16 + i;
      y1T[(size_t)j * ER + e0 + lane] = f2bf(tile[lane][j]);
    }
    __syncthreads();
  }
  atomicAdd(&s1[lane], ssl);
  atomicAdd(&s2[lane], sql);
  __syncthreads();
  if (threadIdx.x < 64) {
    atomicAdd(&ssum[threadIdx.x], s1[threadIdx.x]);
    atomicAdd(&ssq[threadIdx.x], s2[threadIdx.x]);
  }
}

// ---- e2: thread-per-edge on column-major y1T, NAMED register accumulators.
#define ESTAT(SV, QV, IDX) { \
  float s_ = (SV); float q_ = (QV); \
  s_ += __shfl_down(s_, 32, 64); q_ += __shfl_down(q_, 32, 64); \
  s_ += __shfl_down(s_, 16, 64); q_ += __shfl_down(q_, 16, 64); \
  s_ += __shfl_down(s_, 8, 64);  q_ += __shfl_down(q_, 8, 64); \
  s_ += __shfl_down(s_, 4, 64);  q_ += __shfl_down(q_, 4, 64); \
  s_ += __shfl_down(s_, 2, 64);  q_ += __shfl_down(q_, 2, 64); \
  s_ += __shfl_down(s_, 1, 64);  q_ += __shfl_down(q_, 1, 64); \
  if ((threadIdx.x & 63) == 0) { atomicAdd(&s1[IDX], s_); atomicAdd(&s2[IDX], q_); } }

__global__ __launch_bounds__(256) void e2_kernel(const unsigned short* __restrict__ y1T,
                                                 const float* __restrict__ bnp3,
                                                 const float* __restrict__ W,   // [64,16]
                                                 const float* __restrict__ b,   // [16]
                                                 unsigned short* __restrict__ y2T,
                                                 float* __restrict__ ssum,
                                                 float* __restrict__ ssq) {
  __shared__ float Wl[1024], bl[16], sc[64], sh[64], s1[16], s2[16];
  for (int i = threadIdx.x; i < 1024; i += 256) Wl[i] = W[i];
  if (threadIdx.x < 16) {
    bl[threadIdx.x] = b[threadIdx.x];
    s1[threadIdx.x] = 0.0f;
    s2[threadIdx.x] = 0.0f;
  }
  if (threadIdx.x < 64) { sc[threadIdx.x] = bnp3[threadIdx.x]; sh[threadIdx.x] = bnp3[64 + threadIdx.x]; }
  __syncthreads();
  const float4* bl4 = (const float4*)bl;
  const float4* Wl4 = (const float4*)Wl;
#define E2_DECL(I) float4 B##I; \
  float4 SA##I = make_float4(0.f, 0.f, 0.f, 0.f); \
  float4 SQ##I = make_float4(0.f, 0.f, 0.f, 0.f);
  REP4(E2_DECL)
  int stride = gridDim.x * 256;
  for (int e = blockIdx.x * 256 + threadIdx.x; e < ER; e += stride) {
#define E2_INIT(I) B##I = bl4[I];
    REP4(E2_INIT)
#pragma unroll 4
    for (int k = 0; k < 64; ++k) {
      float z = fmaxf(fmaf(bf2f(y1T[(size_t)k * ER + e]), sc[k], sh[k]), 0.0f);
#define E2_FMA(I) { float4 w_ = Wl4[(k << 2) + (I)]; \
      B##I.x = fmaf(z, w_.x, B##I.x); B##I.y = fmaf(z, w_.y, B##I.y); \
      B##I.z = fmaf(z, w_.z, B##I.z); B##I.w = fmaf(z, w_.w, B##I.w); }
      REP4(E2_FMA)
    }
#define E2_OUT(I) \
    y2T[(size_t)(4 * (I) + 0) * ER + e] = f2bf(B##I.x); SA##I.x += B##I.x; SQ##I.x = fmaf(B##I.x, B##I.x, SQ##I.x); \
    y2T[(size_t)(4 * (I) + 1) * ER + e] = f2bf(B##I.y); SA##I.y += B##I.y; SQ##I.y = fmaf(B##I.y, B##I.y, SQ##I.y); \
    y2T[(size_t)(4 * (I) + 2) * ER + e] = f2bf(B##I.z); SA##I.z += B##I.z; SQ##I.z = fmaf(B##I.z, B##I.z, SQ##I.z); \
    y2T[(size_t)(4 * (I) + 3) * ER + e] = f2bf(B##I.w); SA##I.w += B##I.w; SQ##I.w = fmaf(B##I.w, B##I.w, SQ##I.w);
    REP4(E2_OUT)
  }
#define E2_RED(I) ESTAT(SA##I.x, SQ##I.x, 4 * (I) + 0) ESTAT(SA##I.y, SQ##I.y, 4 * (I) + 1) \
                  ESTAT(SA##I.z, SQ##I.z, 4 * (I) + 2) ESTAT(SA##I.w, SQ##I.w, 4 * (I) + 3)
  REP4(E2_RED)
  __syncthreads();
  if (threadIdx.x < 16) {
    atomicAdd(&ssum[threadIdx.x], s1[threadIdx.x]);
    atomicAdd(&ssq[threadIdx.x], s2[threadIdx.x]);
  }
}

__global__ __launch_bounds__(256) void e3_kernel(const unsigned short* __restrict__ y2T,
                                                 const float* __restrict__ bnp4,
                                                 const float* __restrict__ w3,
                                                 const float* __restrict__ b3,
                                                 float* __restrict__ out) {
  __shared__ float sc[16], sh[16], wl[16];
  if (threadIdx.x < 16) {
    sc[threadIdx.x] = bnp4[threadIdx.x];
    sh[threadIdx.x] = bnp4[16 + threadIdx.x];
    wl[threadIdx.x] = w3[threadIdx.x];
  }
  __syncthreads();
  int e = blockIdx.x * 256 + threadIdx.x;
  if (e >= ER) return;
  float acc = b3[0];
#pragma unroll
  for (int j = 0; j < 16; ++j) {
    float v = bf2f(y2T[(size_t)j * ER + e]);
    float z = fmaxf(fmaf(v, sc[j], sh[j]), 0.0f);
    acc = fmaf(z, wl[j], acc);
  }
  out[e] = acc;
}

// ---------------- host ----------------
extern "C" void kernel_launch(void* const* d_in, const int* in_sizes, int n_in,
                              void* d_out, int out_size, void* d_ws, size_t ws_size,
                              hipStream_t stream) {
  const float* u2e = (const float*)d_in[0];
  const float* v2e = (const float*)d_in[1];
  const float* W_self = (const float*)d_in[2];
  const float* b_self = (const float*)d_in[3];
  const float* W_neigh = (const float*)d_in[4];
  const float* Wur1 = (const float*)d_in[5];
  const float* bur1 = (const float*)d_in[6];
  const float* Wur2 = (const float*)d_in[7];
  const float* bur2 = (const float*)d_in[8];
  const float* Wvr1 = (const float*)d_in[9];
  const float* bvr1 = (const float*)d_in[10];
  const float* Wvr2 = (const float*)d_in[11];
  const float* bvr2 = (const float*)d_in[12];
  const float* Wuv1 = (const float*)d_in[13];
  const float* buv1 = (const float*)d_in[14];
  const float* Wuv2 = (const float*)d_in[15];
  const float* buv2 = (const float*)d_in[16];
  const float* Wuv3 = (const float*)d_in[17];
  const float* buv3 = (const float*)d_in[18];
  const float* bn_gamma = (const float*)d_in[19];
  const float* bn_beta = (const float*)d_in[20];
  const float* bn4_gamma = (const float*)d_in[21];
  const float* bn4_beta = (const float*)d_in[22];
  const int* social_src = (const int*)d_in[23];
  const int* social_dst = (const int*)d_in[24];
  const int* rates_src = (const int*)d_in[25];
  const int* rates_dst = (const int*)d_in[26];
  float* out = (float*)d_out;
  float* ws = (float*)d_ws;

  float* A = ws + OFF_A;
  float* Cb = ws + OFF_C;
  float* Db = ws + OFF_D;
  float* Eb = ws + OFF_E;
  float* Fb = ws + OFF_F;
  float* wcomb = ws + OFF_WCOMB;
  float* stats = ws + OFF_STATS;
  float* bnp = ws + OFF_BNP;
  char* y1base = (char*)d_ws + OFF_Y1_BYTES;
  int* idx_s  = (int*)(y1base + CSR_IDX_S);
  int* idx_ru = (int*)(y1base + CSR_IDX_RU);
  int* idx_v  = (int*)(y1base + CSR_IDX_V);
  int* cnt_s  = (int*)(y1base + CSR_CNT_S);
  int* cnt_ru = (int*)(y1base + CSR_CNT_RU);
  int* cnt_v  = (int*)(y1base + CSR_CNT_V);
  int* cur_s  = (int*)(y1base + CSR_CUR_S);
  int* cur_ru = (int*)(y1base + CSR_CUR_RU);
  int* cur_v  = (int*)(y1base + CSR_CUR_V);
  int* off_s  = (int*)(y1base + CSR_OFF_S);
  int* off_ru = (int*)(y1base + CSR_OFF_RU);
  int* off_v  = (int*)(y1base + CSR_OFF_V);
  unsigned short* y1T = (unsigned short*)y1base;
  unsigned short* y2T = (unsigned short*)((char*)d_ws + OFF_Y2_BYTES);

  hipMemsetAsync(cnt_s, 0, 3 * (size_t)NU * sizeof(int), stream);
  hipMemsetAsync(stats, 0, 464 * sizeof(float), stream);

  wcomb_kernel<<<16, 256, 0, stream>>>(W_self, b_self, wcomb);

  hist_kernel<<<2048, 256, 0, stream>>>(social_dst, rates_src, rates_dst, cnt_s, cnt_ru, cnt_v);
  scan3_kernel<<<3, 1024, 0, stream>>>(cnt_s, NU, off_s, cur_s,
                                       cnt_ru, NU, off_ru, cur_ru,
                                       cnt_v, NV, off_v, cur_v);
  scatter_kernel<<<2048, 256, 0, stream>>>(social_src, social_dst, rates_src, rates_dst,
                                           cur_s, cur_ru, cur_v, idx_s, idx_ru, idx_v);
  gmean_kernel<<<(NU * 64 + 255) / 256, 256, 0, stream>>>(u2e, off_s, idx_s, NU, A);
  gmean_kernel<<<(NU * 64 + 255) / 256, 256, 0, stream>>>(v2e, off_ru, idx_ru, NU, Cb);
  gmean_kernel<<<(NV * 64 + 255) / 256, 256, 0, stream>>>(u2e, off_v, idx_v, NV, Db);

  hu_kernel<<<(NU + 255) / 256, 256, 0, stream>>>(u2e, wcomb, W_neigh, A, Cb, Eb);
  hv_kernel<<<(NV + 255) / 256, 256, 0, stream>>>(v2e, W_self, b_self, W_neigh, Db, Fb);

  lin_stats_kernel<<<(NU + 255) / 256, 256, 0, stream>>>(Eb, Wur1, bur1, NU, A, stats + 0, stats + 64);
  lin_stats_kernel<<<(NV + 255) / 256, 256, 0, stream>>>(Fb, Wvr1, bvr1, NV, Cb, stats + 128, stats + 192);

  bn_final_kernel<<<1, 64, 0, stream>>>(stats + 0, stats + 64, bn_gamma, bn_beta, (float)NU, 64, bnp);
  bn_final_kernel<<<1, 64, 0, stream>>>(stats + 128, stats + 192, bn_gamma + 64, bn_beta + 64, (float)NV, 64, bnp + 128);

  bnrelu_lin_kernel<<<(NU + 255) / 256, 256, 0, stream>>>(A, bnp, Wur2, bur2, NU, Db);
  bnrelu_lin_kernel<<<(NV + 255) / 256, 256, 0, stream>>>(Cb, bnp + 128, Wvr2, bvr2, NV, Eb);

  e1_kernel<<<2048, 256, 0, stream>>>(Db, Eb, rates_src, rates_dst, Wuv1, buv1, y1T,
                                      stats + 256, stats + 320);
  bn_final_kernel<<<1, 64, 0, stream>>>(stats + 256, stats + 320, bn_gamma + 128, bn_beta + 128,
                                        (float)ER, 64, bnp + 256);
  e2_kernel<<<2048, 256, 0, stream>>>(y1T, bnp + 256, Wuv2, buv2, y2T,
                                      stats + 384, stats + 400);
  bn_final_kernel<<<1, 16, 0, stream>>>(stats + 384, stats + 400, bn4_gamma, bn4_beta,
                                        (float)ER, 16, bnp + 384);
  e3_kernel<<<(ER + 255) / 256, 256, 0, stream>>>(y2T, bnp + 384, Wuv3, buv3, out);
}